// Round 12
// baseline (940.469 us; speedup 1.0000x reference)
//
#include <hip/hip_runtime.h>
#include <hip/hip_bf16.h>
#include <math.h>

#define B_ 128
#define S_ 100
#define W_ 20
#define D_ 192
#define L_ 6
#define H_ 8
#define DFF_ 256
#define DH_ 24
#define BS_ (B_*S_)
#define THREED_ 576

typedef short short8 __attribute__((ext_vector_type(8)));
typedef short short4v __attribute__((ext_vector_type(4)));
typedef float floatx16 __attribute__((ext_vector_type(16)));

__device__ __forceinline__ float posenc(int s, int c) {
  float freq = expf(-logf(10000.f) * (float)(2 * (c >> 1)) / (float)D_);
  float ang = (float)s * freq;
  return (c & 1) ? cosf(ang) : sinf(ang);
}

__device__ __forceinline__ short8 ld_frag8(const __hip_bfloat16* p) {
  short4v lo = *(const short4v*)p;
  short4v hi = *(const short4v*)(p + 4);
  short8 r;
  r[0]=lo[0]; r[1]=lo[1]; r[2]=lo[2]; r[3]=lo[3];
  r[4]=hi[0]; r[5]=hi[1]; r[6]=hi[2]; r[7]=hi[3];
  return r;
}

// ---------------------------------------------------------------------------
// Merged weight conversion + encoder precompute. 2003 blocks.
// WSPbf[o][j] (128x64 bf16, B-operand layout for the encoder MFMA).
// ---------------------------------------------------------------------------
__global__ __launch_bounds__(256)
void convertprep_kernel(
    const float* __restrict__ s0, __hip_bfloat16* __restrict__ d0,
    const float* __restrict__ s1, __hip_bfloat16* __restrict__ d1,
    const float* __restrict__ s2, __hip_bfloat16* __restrict__ d2,
    const float* __restrict__ s3, __hip_bfloat16* __restrict__ d3,
    const float* __restrict__ te, const float* __restrict__ ce,
    const float* __restrict__ pe, const float* __restrict__ wfw,
    const float* __restrict__ wfb, const float* __restrict__ sw2,
    const float* __restrict__ sb2,
    float* __restrict__ TE2, float* __restrict__ CE2,
    float* __restrict__ PE2, __hip_bfloat16* __restrict__ WSPbf,
    float* __restrict__ wfb2)
{
  int b = blockIdx.x, tid = threadIdx.x;
  if (b < 720) {
    const float* s; __hip_bfloat16* d; int base;
    if      (b < 324) { s = s0; d = d0; base = b; }
    else if (b < 432) { s = s1; d = d1; base = b - 324; }
    else if (b < 576) { s = s2; d = d2; base = b - 432; }
    else              { s = s3; d = d3; base = b - 576; }
    int i = (base * 256 + tid) * 8;
    float4 v0 = *(const float4*)(s + i);
    float4 v1 = *(const float4*)(s + i + 4);
    __hip_bfloat162* d2p = (__hip_bfloat162*)(d + i);
    d2p[0] = __float22bfloat162_rn(make_float2(v0.x, v0.y));
    d2p[1] = __float22bfloat162_rn(make_float2(v0.z, v0.w));
    d2p[2] = __float22bfloat162_rn(make_float2(v1.x, v1.y));
    d2p[3] = __float22bfloat162_rn(make_float2(v1.z, v1.w));
    return;
  }
  int blk = b - 720;
  if (blk < 1250) {
    int item = blk * 256 + tid;
    int v = item >> 7, o = item & 127;
    const float* src; float* dst; int base, vv;
    if (v < 1000)      { src = te; dst = TE2; base = 0;  vv = v; }
    else if (v < 1500) { src = ce; dst = CE2; base = 32; vv = v - 1000; }
    else               { src = pe; dst = PE2; base = 64; vv = v - 1500; }
    float a = 0.f;
    #pragma unroll 8
    for (int k = 0; k < 32; ++k) a += src[vv * 32 + k] * wfw[o * 128 + base + k];
    dst[vv * 128 + o] = a;
  } else if (blk < 1282) {
    int item = (blk - 1250) * 256 + tid;
    int j = item >> 7, o = item & 127;
    float a = 0.f;
    #pragma unroll 8
    for (int k = 0; k < 32; ++k) a += wfw[o * 128 + 96 + k] * sw2[k * 64 + j];
    WSPbf[o * 64 + j] = __float2bfloat16(a);
  } else if (tid < 128) {
    float a = wfb[tid];
    #pragma unroll 8
    for (int k = 0; k < 32; ++k) a += wfw[tid * 128 + 96 + k] * sb2[k];
    wfb2[tid] = a;
  }
}

// ---------------------------------------------------------------------------
// Encoder v6 (MFMA + hoisted gather pass). 8 bs (160 rows)/block, grid 1600,
// 256 threads = 4 waves.
// R11 fix of R9's encode4 (236us): the epilogue's 240-deep DEPENDENT gather
// chain is replaced by a streaming pre-pass: after the MFMA (acc in regs),
// a grid-stride loop computes Gsum = TE2[t]+CE2[ci]+PE2[p]+wfb2 with fully
// independent coalesced loads into LDS bf16 (pitch 129, aliasing the dead
// A/B staging arena). Epilogue = relu(acc+Gsum)*mask + LDS atomic only.
// LDS ~50 KB -> 3 blocks/CU.
// ---------------------------------------------------------------------------
__global__ __launch_bounds__(256)
void encode6_kernel(
    const int* __restrict__ title_idx, const int* __restrict__ class_idx,
    const int* __restrict__ process_idx, const int* __restrict__ activity_type,
    const float* __restrict__ mouse_pos, const float* __restrict__ rect,
    const float* __restrict__ flags, const float* __restrict__ keyboard_active,
    const float* __restrict__ window_mask,
    const float* __restrict__ sw1, const float* __restrict__ sb1,
    const float* __restrict__ TE2, const float* __restrict__ CE2,
    const float* __restrict__ PE2, const __hip_bfloat16* __restrict__ WSPbf,
    const float* __restrict__ wfb2,
    const float* __restrict__ mw1, const float* __restrict__ mb1,
    const float* __restrict__ mw2, const float* __restrict__ mb2,
    const float* __restrict__ act_emb, const float* __restrict__ kbw,
    const float* __restrict__ kbb,
    const float* __restrict__ afw, const float* __restrict__ afb,
    float* __restrict__ x, __hip_bfloat16* __restrict__ xb)
{
  __shared__ __align__(16) char arena[41472];  // Asl(23040)+Bsl(18432) | Gsum(41280)
  __shared__ __align__(16) int idxT[160];
  __shared__ __align__(16) int idxC[160];
  __shared__ __align__(16) int idxP[160];
  __shared__ __align__(16) float maskS[160];
  __shared__ float avgS[8 * 132];
  __shared__ float afA[4][68], afB[4][68];
  __hip_bfloat16* Asl  = (__hip_bfloat16*)arena;            // 160 x 72
  __hip_bfloat16* Bsl  = (__hip_bfloat16*)(arena + 23040);  // 128 x 72
  __hip_bfloat16* Gsum = (__hip_bfloat16*)arena;            // 160 x 129 (after MFMA)

  int tid = threadIdx.x;
  int bs0 = blockIdx.x * 8;
  int row0 = bs0 * W_;
  int lane = tid & 63, w = tid >> 6;
  int m32 = lane & 31, half = lane >> 5;

  for (int e = tid; e < 8 * 132; e += 256) avgS[e] = 0.f;
  // stage B (WSPbf): 128 cols x 64 k
  for (int e = tid; e < 1024; e += 256) {
    int col = e >> 3, seg = e & 7;
    *(float4*)&Bsl[col * 72 + seg * 8] = *(const float4*)&WSPbf[col * 64 + seg * 8];
  }
  // thread-per-row: h1 MLP -> Asl bf16; idx/mask staging (validated in R9)
  if (tid < 160) {
    int row = tid, rg = row0 + row;
    float4 rc = *(const float4*)(rect + (size_t)rg * 4);
    float f0 = flags[rg * 2], f1 = flags[rg * 2 + 1];
    #pragma unroll 8
    for (int j = 0; j < 64; ++j) {
      const float* w1 = sw1 + j * 6;
      float a = sb1[j] + w1[0]*rc.x + w1[1]*rc.y + w1[2]*rc.z + w1[3]*rc.w
                       + w1[4]*f0 + w1[5]*f1;
      Asl[row * 72 + j] = __float2bfloat16(fmaxf(a, 0.f));
    }
    idxT[row] = title_idx[rg];
    idxC[row] = class_idx[rg];
    idxP[row] = process_idx[rg];
    maskS[row] = window_mask[rg];
  }
  __syncthreads();

  // ---- MFMA: C[160x128] = h1[160x64] @ WSP[128x64]^T (validated in R9) ----
  int col = w * 32 + m32;
  floatx16 acc[5];
  #pragma unroll
  for (int mt = 0; mt < 5; ++mt)
    #pragma unroll
    for (int r = 0; r < 16; ++r) acc[mt][r] = 0.f;
  #pragma unroll
  for (int kc = 0; kc < 4; ++kc) {
    int ko = kc * 16 + half * 8;
    short8 bf = *(const short8*)&Bsl[col * 72 + ko];
    #pragma unroll
    for (int mt = 0; mt < 5; ++mt) {
      short8 a = *(const short8*)&Asl[(mt * 32 + m32) * 72 + ko];
      acc[mt] = __builtin_amdgcn_mfma_f32_32x32x16_bf16(a, bf, acc[mt], 0, 0, 0);
    }
  }
  __syncthreads();   // Asl/Bsl dead; Gsum may overwrite

  // ---- streaming gather pre-pass (independent, coalesced) ----
  for (int e = tid; e < 160 * 128; e += 256) {
    int row = e >> 7, c2 = e & 127;
    int t  = idxT[row];
    int ci = idxC[row];
    int p  = idxP[row];
    float G = TE2[(size_t)t * 128 + c2] + CE2[(size_t)ci * 128 + c2]
            + PE2[(size_t)p * 128 + c2] + wfb2[c2];
    Gsum[row * 129 + c2] = __float2bfloat16(G);
  }
  __syncthreads();

  // ---- epilogue: relu(acc + Gsum)*mask -> LDS atomic avg ----
  #pragma unroll
  for (int mt = 0; mt < 5; ++mt) {
    int rowb = mt * 32 + 4 * half;
    #pragma unroll
    for (int r = 0; r < 16; ++r) {
      int row = rowb + (r & 3) + 8 * (r >> 2);
      float val = fmaxf(acc[mt][r] + __bfloat162float(Gsum[row * 129 + col]), 0.f)
                * maskS[row];
      atomicAdd(&avgS[(row / 20) * 132 + col], val);
    }
  }
  __syncthreads();

  // x[:, 0:128] = avg + posenc
  for (int e = tid; e < 8 * 128; e += 256) {
    int bsl = e >> 7, c2 = e & 127;
    int bsg = bs0 + bsl;
    float v = avgS[bsl * 132 + c2] * (1.f / (float)W_) + posenc(bsg % S_, c2);
    x[(size_t)bsg * D_ + c2] = v;
    xb[(size_t)bsg * D_ + c2] = __float2bfloat16(v);
  }

  // activity fusion -> cols 128..191, 2 passes of 4 bs (validated)
  for (int pass = 0; pass < 2; ++pass) {
    int bl = tid >> 6, ln = tid & 63;
    int bsg = bs0 + pass * 4 + bl;
    __syncthreads();
    if (ln < 32) {
      float mx = mouse_pos[bsg * 2 + 0] * (1.f / 1920.f);
      float my = mouse_pos[bsg * 2 + 1] * (1.f / 1080.f);
      afA[bl][ln] = fmaxf(mw1[ln * 2] * mx + mw1[ln * 2 + 1] * my + mb1[ln], 0.f);
    }
    __syncthreads();
    float cv;
    if (ln < 32) {
      float a = mb2[ln];
      #pragma unroll 8
      for (int k = 0; k < 32; ++k) a += mw2[ln * 32 + k] * afA[bl][k];
      cv = a;
    } else if (ln < 48) {
      cv = act_emb[activity_type[bsg] * 16 + (ln - 32)];
    } else {
      cv = kbw[ln - 48] * keyboard_active[bsg] + kbb[ln - 48];
    }
    __syncthreads();
    afB[bl][ln] = cv;
    __syncthreads();
    {
      float a = afb[ln];
      const float4* w4 = (const float4*)(afw + ln * 64);
      const float4* cp = (const float4*)&afB[bl][0];
      #pragma unroll
      for (int k4 = 0; k4 < 16; ++k4) {
        float4 ww = w4[k4], c2 = cp[k4];
        a += ww.x*c2.x + ww.y*c2.y + ww.z*c2.z + ww.w*c2.w;
      }
      float v = fmaxf(a, 0.f);
      int cg = 128 + ln;
      float ovv = v + posenc(bsg % S_, cg);
      x[(size_t)bsg * D_ + cg] = ovv;
      xb[(size_t)bsg * D_ + cg] = __float2bfloat16(ovv);
    }
  }
}

// ---------------------------------------------------------------------------
// Fused qkv + attention (validated R7). One block per (b,h), 256 threads.
// R11: Ps now aliases Asl/Bsl/Qs/Ks (all dead once QK^T is done) -> arena
// 64000 -> 47104 B -> 3 blocks/CU (was 2). One extra barrier before Ps store.
// ---------------------------------------------------------------------------
__global__ __launch_bounds__(256)
void qkvattn_kernel(const __hip_bfloat16* __restrict__ xb,
                    const __hip_bfloat16* __restrict__ Wq,
                    const float* __restrict__ qb,
                    __hip_bfloat16* __restrict__ o)
{
  __shared__ __align__(16) char smem[47104];
  __hip_bfloat16* Asl = (__hip_bfloat16*)smem;             // 128*40
  __hip_bfloat16* Bsl = (__hip_bfloat16*)(smem + 10240);   // 96*40
  __hip_bfloat16* Qs  = (__hip_bfloat16*)(smem + 17920);   // 128*40
  __hip_bfloat16* Ks  = (__hip_bfloat16*)(smem + 28160);   // 128*40
  __hip_bfloat16* Vt  = (__hip_bfloat16*)(smem + 38400);   // 32*136
  __hip_bfloat16* Ps  = (__hip_bfloat16*)smem;             // 128*136 (post-QK^T)

  int bh = blockIdx.x;
  int hh = bh & 7, b = bh >> 3;
  int tid = threadIdx.x, lane = tid & 63, w = tid >> 6;
  int m32 = lane & 31, half = lane >> 5;

  for (int e = tid; e < (32 * 136) / 8; e += 256)
    ((float4*)Vt)[e] = make_float4(0.f, 0.f, 0.f, 0.f);

  floatx16 acc[3];
  #pragma unroll
  for (int t = 0; t < 3; ++t)
    #pragma unroll
    for (int r = 0; r < 16; ++r) acc[t][r] = 0.f;

  for (int k0 = 0; k0 < D_; k0 += 32) {
    {
      int r = tid >> 1, h2 = tid & 1;
      int rr = r < S_ ? r : S_ - 1;
      const float4* s = (const float4*)&xb[(size_t)(b * S_ + rr) * D_ + k0 + h2 * 16];
      float4* d = (float4*)&Asl[r * 40 + h2 * 16];
      d[0] = s[0]; d[1] = s[1];
    }
    if (tid < 192) {
      int r = tid >> 1, h2 = tid & 1;
      int t = r >> 5, j = r & 31;
      float4 v0 = make_float4(0.f, 0.f, 0.f, 0.f), v1 = v0;
      if (j < DH_) {
        const float4* s =
            (const float4*)&Wq[(size_t)(t * D_ + hh * DH_ + j) * D_ + k0 + h2 * 16];
        v0 = s[0]; v1 = s[1];
      }
      float4* d = (float4*)&Bsl[r * 40 + h2 * 16];
      d[0] = v0; d[1] = v1;
    }
    __syncthreads();
    #pragma unroll
    for (int kc = 0; kc < 2; ++kc) {
      int ko = kc * 16 + half * 8;
      short8 a = *(const short8*)&Asl[(w * 32 + m32) * 40 + ko];
      #pragma unroll
      for (int t = 0; t < 3; ++t) {
        short8 bf = *(const short8*)&Bsl[(t * 32 + m32) * 40 + ko];
        acc[t] = __builtin_amdgcn_mfma_f32_32x32x16_bf16(a, bf, acc[t], 0, 0, 0);
      }
    }
    __syncthreads();
  }
  {
    bool dv = (m32 < DH_);
    float bq = dv ? qb[0 * D_ + hh * DH_ + m32] : 0.f;
    float bk = dv ? qb[1 * D_ + hh * DH_ + m32] : 0.f;
    float bv = dv ? qb[2 * D_ + hh * DH_ + m32] : 0.f;
    #pragma unroll
    for (int r = 0; r < 16; ++r) {
      int row = w * 32 + (r & 3) + 8 * (r >> 2) + 4 * half;
      Qs[row * 40 + m32] = __float2bfloat16(dv ? acc[0][r] + bq : 0.f);
      Ks[row * 40 + m32] = __float2bfloat16(dv ? acc[1][r] + bk : 0.f);
      if (dv) Vt[m32 * 136 + row] = __float2bfloat16(acc[2][r] + bv);
    }
  }
  __syncthreads();

  floatx16 sc[4];
  #pragma unroll
  for (int nt = 0; nt < 4; ++nt)
    #pragma unroll
    for (int r = 0; r < 16; ++r) sc[nt][r] = 0.f;
  #pragma unroll
  for (int kc = 0; kc < 2; ++kc) {
    int ko = kc * 16 + half * 8;
    short8 a = *(const short8*)&Qs[(w * 32 + m32) * 40 + ko];
    #pragma unroll
    for (int nt = 0; nt < 4; ++nt) {
      short8 bf = *(const short8*)&Ks[(nt * 32 + m32) * 40 + ko];
      sc[nt] = __builtin_amdgcn_mfma_f32_32x32x16_bf16(a, bf, sc[nt], 0, 0, 0);
    }
  }
  __syncthreads();   // all waves done reading Qs/Ks before Ps overwrites them

  const float scale = 0.20412414523193154f;
  float rinv[16];
  #pragma unroll
  for (int r = 0; r < 16; ++r) {
    float mx = -1e30f;
    #pragma unroll
    for (int nt = 0; nt < 4; ++nt) {
      float s = sc[nt][r] * scale;
      if (nt == 3 && m32 >= 4) s = -1e30f;
      sc[nt][r] = s;
      mx = fmaxf(mx, s);
    }
    #pragma unroll
    for (int off = 1; off < 32; off <<= 1) mx = fmaxf(mx, __shfl_xor(mx, off));
    float sum = 0.f;
    #pragma unroll
    for (int nt = 0; nt < 4; ++nt) {
      float e = expf(sc[nt][r] - mx);
      sc[nt][r] = e;
      sum += e;
    }
    #pragma unroll
    for (int off = 1; off < 32; off <<= 1) sum += __shfl_xor(sum, off);
    rinv[r] = 1.f / sum;
  }
  #pragma unroll
  for (int r = 0; r < 16; ++r) {
    int rowl = (r & 3) + 8 * (r >> 2) + 4 * half;
    #pragma unroll
    for (int nt = 0; nt < 4; ++nt)
      Ps[(w * 32 + rowl) * 136 + nt * 32 + m32] = __float2bfloat16(sc[nt][r]);
  }
  // Ps is wave-private — no barrier.

  floatx16 ov;
  #pragma unroll
  for (int r = 0; r < 16; ++r) ov[r] = 0.f;
  #pragma unroll
  for (int kt = 0; kt < 8; ++kt) {
    int ko = kt * 16 + half * 8;
    short8 a = *(const short8*)&Ps[(w * 32 + m32) * 136 + ko];
    short8 bf = *(const short8*)&Vt[m32 * 136 + ko];
    ov = __builtin_amdgcn_mfma_f32_32x32x16_bf16(a, bf, ov, 0, 0, 0);
  }
  #pragma unroll
  for (int r = 0; r < 16; ++r) {
    int rowl = (r & 3) + 8 * (r >> 2) + 4 * half;
    int q = w * 32 + rowl;
    if (m32 < DH_ && q < S_)
      o[((size_t)(b * S_ + q)) * D_ + hh * DH_ + m32] =
          __float2bfloat16(ov[r] * rinv[r]);
  }
}

// ---------------------------------------------------------------------------
// Fused out-proj+LN1 + ff1+ff2+LN2 (validated R10). 200 blocks, 256 threads.
// ---------------------------------------------------------------------------
__global__ __launch_bounds__(256)
void outffln_kernel(const __hip_bfloat16* __restrict__ attb,
                    const __hip_bfloat16* __restrict__ Wo, const float* __restrict__ bo,
                    const float* __restrict__ g1, const float* __restrict__ b1v,
                    const __hip_bfloat16* __restrict__ W1, const float* __restrict__ b1,
                    const __hip_bfloat16* __restrict__ W2, const float* __restrict__ b2,
                    const float* __restrict__ g2, const float* __restrict__ b2v,
                    float* __restrict__ x, __hip_bfloat16* __restrict__ xb)
{
  __shared__ __align__(16) char arena[59904];
  __hip_bfloat16* AslA = (__hip_bfloat16*)arena;             // 64*40
  __hip_bfloat16* BslA = (__hip_bfloat16*)(arena + 5120);    // 192*40
  __hip_bfloat16* C1   = (__hip_bfloat16*)arena;             // 64*260
  __hip_bfloat16* AslB = (__hip_bfloat16*)(arena + 33280);   // 64*40
  __hip_bfloat16* BslB = (__hip_bfloat16*)(arena + 38400);   // 256*40
  float (*psum)[2] = (float(*)[2])(arena + 58880);
  float (*psq)[2]  = (float(*)[2])(arena + 59392);

  int tid = threadIdx.x, lane = tid & 63, w = tid >> 6;
  int m32 = lane & 31, half = lane >> 5;
  int mt = w & 1, ng = w >> 1;
  int bm = blockIdx.x * 64;

  // ================= phase A: out-proj + residual + LN1 =================
  floatx16 accA[3];
  #pragma unroll
  for (int j = 0; j < 3; ++j)
    #pragma unroll
    for (int r = 0; r < 16; ++r) accA[j][r] = 0.f;

  for (int k0 = 0; k0 < D_; k0 += 32) {
    if (tid < 128) {
      int r = tid >> 1, h = tid & 1;
      const float4* s = (const float4*)(attb + (size_t)(bm + r) * D_ + k0 + h * 16);
      float4* d = (float4*)&AslA[r * 40 + h * 16];
      d[0] = s[0]; d[1] = s[1];
    }
    for (int e = tid; e < 384; e += 256) {
      int r = e >> 1, h = e & 1;
      const float4* s = (const float4*)(Wo + (size_t)r * D_ + k0 + h * 16);
      float4* d = (float4*)&BslA[r * 40 + h * 16];
      d[0] = s[0]; d[1] = s[1];
    }
    __syncthreads();
    #pragma unroll
    for (int kc = 0; kc < 2; ++kc) {
      int ko = kc * 16 + half * 8;
      short8 a = *(const short8*)&AslA[(mt * 32 + m32) * 40 + ko];
      #pragma unroll
      for (int j = 0; j < 3; ++j) {
        short8 bf = *(const short8*)&BslA[((ng * 3 + j) * 32 + m32) * 40 + ko];
        accA[j] = __builtin_amdgcn_mfma_f32_32x32x16_bf16(a, bf, accA[j], 0, 0, 0);
      }
    }
    __syncthreads();
  }
  {
    int rowb = mt * 32 + 4 * half;
    #pragma unroll
    for (int r = 0; r < 16; ++r) {
      int rl = rowb + (r & 3) + 8 * (r >> 2);
      int row = bm + rl;
      float p = 0.f;
      #pragma unroll
      for (int j = 0; j < 3; ++j) {
        int col = (ng * 3 + j) * 32 + m32;
        float t = accA[j][r] + bo[col] + x[(size_t)row * D_ + col];
        accA[j][r] = t;
        p += t;
      }
      #pragma unroll
      for (int off = 1; off < 32; off <<= 1) p += __shfl_xor(p, off);
      if (m32 == 0) psum[rl][ng] = p;
    }
    __syncthreads();
    float mean[16];
    #pragma unroll
    for (int r = 0; r < 16; ++r) {
      int rl = rowb + (r & 3) + 8 * (r >> 2);
      mean[r] = (psum[rl][0] + psum[rl][1]) * (1.f / (float)D_);
    }
    #pragma unroll
    for (int r = 0; r < 16; ++r) {
      int rl = rowb + (r & 3) + 8 * (r >> 2);
      float s = 0.f;
      #pragma unroll
      for (int j = 0; j < 3; ++j) { float dd = accA[j][r] - mean[r]; s += dd * dd; }
      #pragma unroll
      for (int off = 1; off < 32; off <<= 1) s += __shfl_xor(s, off);
      if (m32 == 0) psq[rl][ng] = s;
    }
    __syncthreads();
    #pragma unroll
    for (int r = 0; r < 16; ++r) {
      int rl = rowb + (r & 3) + 8 * (r >> 2);
      int row = bm + rl;
      float inv = rsqrtf((psq[rl][0] + psq[rl][1]) * (1.f / (float)D_) + 1e-5f);
      #pragma unroll
      for (int j = 0; j < 3; ++j) {
        int col = (ng * 3 + j) * 32 + m32;
        float ovv = (accA[j][r] - mean[r]) * inv * g1[col] + b1v[col];
        x[(size_t)row * D_ + col] = ovv;
        xb[(size_t)row * D_ + col] = __float2bfloat16(ovv);
      }
    }
  }
  __syncthreads();

  // ================= phase B: ff1 + ff2 + residual + LN2 ==========
  floatx16 acc1[4];
  #pragma unroll
  for (int j = 0; j < 4; ++j)
    #pragma unroll
    for (int r = 0; r < 16; ++r) acc1[j][r] = 0.f;

  for (int k0 = 0; k0 < D_; k0 += 32) {
    if (tid < 128) {
      int r = tid >> 1, h = tid & 1;
      const float4* s = (const float4*)(xb + (size_t)(bm + r) * D_ + k0 + h * 16);
      float4* d = (float4*)&AslB[r * 40 + h * 16];
      d[0] = s[0]; d[1] = s[1];
    }
    for (int e = tid; e < 512; e += 256) {
      int r = e >> 1, h = e & 1;
      const float4* s = (const float4*)(W1 + (size_t)r * D_ + k0 + h * 16);
      float4* d = (float4*)&BslB[r * 40 + h * 16];
      d[0] = s[0]; d[1] = s[1];
    }
    __syncthreads();
    #pragma unroll
    for (int kc = 0; kc < 2; ++kc) {
      int ko = kc * 16 + half * 8;
      short8 a = *(const short8*)&AslB[(mt * 32 + m32) * 40 + ko];
      #pragma unroll
      for (int j = 0; j < 4; ++j) {
        short8 bf = *(const short8*)&BslB[((ng * 4 + j) * 32 + m32) * 40 + ko];
        acc1[j] = __builtin_amdgcn_mfma_f32_32x32x16_bf16(a, bf, acc1[j], 0, 0, 0);
      }
    }
    __syncthreads();
  }
  {
    int rowb = mt * 32 + 4 * half;
    #pragma unroll
    for (int j = 0; j < 4; ++j) {
      int col = (ng * 4 + j) * 32 + m32;
      float cb = b1[col];
      #pragma unroll
      for (int r = 0; r < 16; ++r) {
        int row = rowb + (r & 3) + 8 * (r >> 2);
        C1[row * 260 + col] = __float2bfloat16(fmaxf(acc1[j][r] + cb, 0.f));
      }
    }
  }
  __syncthreads();

  floatx16 acc2[3];
  #pragma unroll
  for (int j = 0; j < 3; ++j)
    #pragma unroll
    for (int r = 0; r < 16; ++r) acc2[j][r] = 0.f;

  for (int k0 = 0; k0 < DFF_; k0 += 32) {
    for (int e = tid; e < 384; e += 256) {
      int r = e >> 1, h = e & 1;
      const float4* s = (const float4*)(W2 + (size_t)r * DFF_ + k0 + h * 16);
      float4* d = (float4*)&BslB[r * 40 + h * 16];
      d[0] = s[0]; d[1] = s[1];
    }
    __syncthreads();
    #pragma unroll
    for (int kc = 0; kc < 2; ++kc) {
      int ko = kc * 16 + half * 8;
      short8 a = ld_frag8(&C1[(mt * 32 + m32) * 260 + k0 + ko]);
      #pragma unroll
      for (int j = 0; j < 3; ++j) {
        short8 bf = *(const short8*)&BslB[((ng * 3 + j) * 32 + m32) * 40 + ko];
        acc2[j] = __builtin_amdgcn_mfma_f32_32x32x16_bf16(a, bf, acc2[j], 0, 0, 0);
      }
    }
    __syncthreads();
  }

  int rowb = mt * 32 + 4 * half;
  #pragma unroll
  for (int r = 0; r < 16; ++r) {
    int rl = rowb + (r & 3) + 8 * (r >> 2);
    int row = bm + rl;
    float p = 0.f;
    #pragma unroll
    for (int j = 0; j < 3; ++j) {
      int col = (ng * 3 + j) * 32 + m32;
      float t = acc2[j][r] + b2[col] + x[(size_t)row * D_ + col];
      acc2[j][r] = t;
      p += t;
    }
    #pragma unroll
    for (int off = 1; off < 32; off <<= 1) p += __shfl_xor(p, off);
    if (m32 == 0) psum[rl][ng] = p;
  }
  __syncthreads();
  float mean[16];
  #pragma unroll
  for (int r = 0; r < 16; ++r) {
    int rl = rowb + (r & 3) + 8 * (r >> 2);
    mean[r] = (psum[rl][0] + psum[rl][1]) * (1.f / (float)D_);
  }
  #pragma unroll
  for (int r = 0; r < 16; ++r) {
    int rl = rowb + (r & 3) + 8 * (r >> 2);
    float s = 0.f;
    #pragma unroll
    for (int j = 0; j < 3; ++j) { float dd = acc2[j][r] - mean[r]; s += dd * dd; }
    #pragma unroll
    for (int off = 1; off < 32; off <<= 1) s += __shfl_xor(s, off);
    if (m32 == 0) psq[rl][ng] = s;
  }
  __syncthreads();
  #pragma unroll
  for (int r = 0; r < 16; ++r) {
    int rl = rowb + (r & 3) + 8 * (r >> 2);
    int row = bm + rl;
    float inv = rsqrtf((psq[rl][0] + psq[rl][1]) * (1.f / (float)D_) + 1e-5f);
    #pragma unroll
    for (int j = 0; j < 3; ++j) {
      int col = (ng * 3 + j) * 32 + m32;
      float ovv = (acc2[j][r] - mean[r]) * inv * g2[col] + b2v[col];
      x[(size_t)row * D_ + col] = ovv;
      xb[(size_t)row * D_ + col] = __float2bfloat16(ovv);
    }
  }
}

// ---------------------------------------------------------------------------
// Head (fp32): one block per (w,b) slot.
// ---------------------------------------------------------------------------
__global__ __launch_bounds__(256)
void head_kernel(const float* __restrict__ x, const float* __restrict__ noise,
                 const float* __restrict__ pw1, const float* __restrict__ pb1,
                 const float* __restrict__ pw2, const float* __restrict__ pb2,
                 const float* __restrict__ ew1, const float* __restrict__ eb1,
                 const float* __restrict__ ew2, const float* __restrict__ eb2,
                 float* __restrict__ out)
{
  int idx = blockIdx.x;
  int b = idx & 127, w = idx >> 7;
  int tid = threadIdx.x;
  __shared__ float slot[192];
  __shared__ float ph[256];
  __shared__ float eh[128];
  if (tid < 192)
    slot[tid] = x[((size_t)b * S_ + (S_ - 1)) * D_ + tid]
              + noise[((size_t)w * B_ + b) * D_ + tid] * 0.1f;
  __syncthreads();
  {
    const float4* wr = (const float4*)(pw1 + (size_t)tid * D_);
    const float4* sp = (const float4*)slot;
    float a = pb1[tid];
    #pragma unroll 12
    for (int k = 0; k < 48; ++k) {
      float4 wv = wr[k], sv = sp[k];
      a += wv.x*sv.x + wv.y*sv.y + wv.z*sv.z + wv.w*sv.w;
    }
    ph[tid] = fmaxf(a, 0.f);
  }
  if (tid < 128) {
    const float4* wr = (const float4*)(ew1 + (size_t)tid * D_);
    const float4* sp = (const float4*)slot;
    float a = eb1[tid];
    #pragma unroll 12
    for (int k = 0; k < 48; ++k) {
      float4 wv = wr[k], sv = sp[k];
      a += wv.x*sv.x + wv.y*sv.y + wv.z*sv.z + wv.w*sv.w;
    }
    eh[tid] = fmaxf(a, 0.f);
  }
  __syncthreads();
  if (tid < 4) {
    float a = pb2[tid];
    const float4* wr = (const float4*)(pw2 + tid * 256);
    const float4* pp = (const float4*)ph;
    for (int k = 0; k < 64; ++k) {
      float4 wv = wr[k], pv = pp[k];
      a += wv.x*pv.x + wv.y*pv.y + wv.z*pv.z + wv.w*pv.w;
    }
    out[((size_t)b * W_ + w) * 4 + tid] = a;
  }
  if (tid == 4) {
    float a = eb2[0];
    const float4* wr = (const float4*)ew2;
    const float4* pp = (const float4*)eh;
    for (int k = 0; k < 32; ++k) {
      float4 wv = wr[k], pv = pp[k];
      a += wv.x*pv.x + wv.y*pv.y + wv.z*pv.z + wv.w*pv.w;
    }
    out[(size_t)B_ * W_ * 4 + (size_t)b * W_ + w] = 1.f / (1.f + expf(-a));
  }
}

// ---------------------------------------------------------------------------
extern "C" void kernel_launch(void* const* d_in, const int* in_sizes, int n_in,
                              void* d_out, int out_size, void* d_ws, size_t ws_size,
                              hipStream_t stream)
{
  const int*   title_idx       = (const int*)  d_in[0];
  const int*   class_idx       = (const int*)  d_in[1];
  const int*   process_idx     = (const int*)  d_in[2];
  const int*   activity_type   = (const int*)  d_in[3];
  const float* mouse_pos       = (const float*)d_in[4];
  const float* rect            = (const float*)d_in[5];
  const float* flags           = (const float*)d_in[6];
  const float* keyboard_active = (const float*)d_in[7];
  const float* window_mask     = (const float*)d_in[8];
  const float* noise           = (const float*)d_in[9];
  const float* title_emb       = (const float*)d_in[10];
  const float* class_emb       = (const float*)d_in[11];
  const float* process_emb     = (const float*)d_in[12];
  const float* spatial_w1      = (const float*)d_in[13];
  const float* spatial_b1      = (const float*)d_in[14];
  const float* spatial_w2      = (const float*)d_in[15];
  const float* spatial_b2      = (const float*)d_in[16];
  const float* wfuse_w         = (const float*)d_in[17];
  const float* wfuse_b         = (const float*)d_in[18];
  const float* mouse_w1        = (const float*)d_in[19];
  const float* mouse_b1        = (const float*)d_in[20];
  const float* mouse_w2        = (const float*)d_in[21];
  const float* mouse_b2        = (const float*)d_in[22];
  const float* act_emb         = (const float*)d_in[23];
  const float* kbd_w           = (const float*)d_in[24];
  const float* kbd_b           = (const float*)d_in[25];
  const float* afuse_w         = (const float*)d_in[26];
  const float* afuse_b         = (const float*)d_in[27];
  const float* qkv_w           = (const float*)d_in[28];
  const float* qkv_b           = (const float*)d_in[29];
  const float* out_w           = (const float*)d_in[30];
  const float* out_b           = (const float*)d_in[31];
  const float* ff1_w           = (const float*)d_in[32];
  const float* ff1_b           = (const float*)d_in[33];
  const float* ff2_w           = (const float*)d_in[34];
  const float* ff2_b           = (const float*)d_in[35];
  const float* ln1_g           = (const float*)d_in[36];
  const float* ln1_b           = (const float*)d_in[37];
  const float* ln2_g           = (const float*)d_in[38];
  const float* ln2_b           = (const float*)d_in[39];
  const float* proj_w1         = (const float*)d_in[40];
  const float* proj_b1         = (const float*)d_in[41];
  const float* proj_w2         = (const float*)d_in[42];
  const float* proj_b2         = (const float*)d_in[43];
  const float* ex_w1           = (const float*)d_in[44];
  const float* ex_b1           = (const float*)d_in[45];
  const float* ex_w2           = (const float*)d_in[46];
  const float* ex_b2           = (const float*)d_in[47];

  float* out = (float*)d_out;

  // workspace layout
  float* x = (float*)d_ws;                                      // BS*192 f32
  __hip_bfloat16* xb   = (__hip_bfloat16*)(x + (size_t)BS_ * D_);
  __hip_bfloat16* attb = xb   + (size_t)BS_ * D_;
  __hip_bfloat16* wqb  = attb + (size_t)BS_ * D_;
  __hip_bfloat16* wob  = wqb  + (size_t)L_ * THREED_ * D_;
  __hip_bfloat16* wf1b = wob  + (size_t)L_ * D_ * D_;
  __hip_bfloat16* wf2b = wf1b + (size_t)L_ * DFF_ * D_;
  float* TE2  = (float*)(wf2b + (size_t)L_ * D_ * DFF_);        // 1000*128
  float* CE2  = TE2  + 1000 * 128;                              // 500*128
  float* PE2  = CE2  + 500 * 128;                               // 1000*128
  __hip_bfloat16* WSPbf = (__hip_bfloat16*)(PE2 + 1000 * 128);  // 128*64 bf16
  float* wfb2 = (float*)(WSPbf + 128 * 64);                     // 128
  (void)ws_size; (void)n_in; (void)in_sizes; (void)out_size;

  convertprep_kernel<<<2003, 256, 0, stream>>>(
      qkv_w, wqb, out_w, wob, ff1_w, wf1b, ff2_w, wf2b,
      title_emb, class_emb, process_emb, wfuse_w, wfuse_b,
      spatial_w2, spatial_b2, TE2, CE2, PE2, WSPbf, wfb2);

  encode6_kernel<<<BS_ / 8, 256, 0, stream>>>(
      title_idx, class_idx, process_idx, activity_type, mouse_pos, rect, flags,
      keyboard_active, window_mask, spatial_w1, spatial_b1,
      TE2, CE2, PE2, WSPbf, wfb2,
      mouse_w1, mouse_b1, mouse_w2, mouse_b2, act_emb, kbd_w, kbd_b,
      afuse_w, afuse_b, x, xb);

  for (int l = 0; l < L_; ++l) {
    qkvattn_kernel<<<B_ * H_, 256, 0, stream>>>(
        xb, wqb + (size_t)l * THREED_ * D_, qkv_b + (size_t)l * THREED_, attb);
    outffln_kernel<<<BS_ / 64, 256, 0, stream>>>(
        attb, wob + (size_t)l * D_ * D_, out_b + (size_t)l * D_,
        ln1_g + (size_t)l * D_, ln1_b + (size_t)l * D_,
        wf1b + (size_t)l * DFF_ * D_, ff1_b + (size_t)l * DFF_,
        wf2b + (size_t)l * D_ * DFF_, ff2_b + (size_t)l * D_,
        ln2_g + (size_t)l * D_, ln2_b + (size_t)l * D_, x, xb);
  }

  head_kernel<<<W_ * B_, 256, 0, stream>>>(
      x, noise, proj_w1, proj_b1, proj_w2, proj_b2,
      ex_w1, ex_b1, ex_w2, ex_b2, out);
}

// Round 13
// 911.467 us; speedup vs baseline: 1.0318x; 1.0318x over previous
//
#include <hip/hip_runtime.h>
#include <hip/hip_bf16.h>
#include <math.h>

#define B_ 128
#define S_ 100
#define W_ 20
#define D_ 192
#define L_ 6
#define H_ 8
#define DFF_ 256
#define DH_ 24
#define BS_ (B_*S_)
#define THREED_ 576

typedef short short8 __attribute__((ext_vector_type(8)));
typedef short short4v __attribute__((ext_vector_type(4)));
typedef float floatx16 __attribute__((ext_vector_type(16)));

__device__ __forceinline__ float posenc(int s, int c) {
  float freq = expf(-logf(10000.f) * (float)(2 * (c >> 1)) / (float)D_);
  float ang = (float)s * freq;
  return (c & 1) ? cosf(ang) : sinf(ang);
}

__device__ __forceinline__ short8 ld_frag8(const __hip_bfloat16* p) {
  short4v lo = *(const short4v*)p;
  short4v hi = *(const short4v*)(p + 4);
  short8 r;
  r[0]=lo[0]; r[1]=lo[1]; r[2]=lo[2]; r[3]=lo[3];
  r[4]=hi[0]; r[5]=hi[1]; r[6]=hi[2]; r[7]=hi[3];
  return r;
}

// ---------------------------------------------------------------------------
// Merged weight conversion + encoder precompute (R8/R10-validated). 2003 blk.
// ---------------------------------------------------------------------------
__global__ __launch_bounds__(256)
void convertprep_kernel(
    const float* __restrict__ s0, __hip_bfloat16* __restrict__ d0,
    const float* __restrict__ s1, __hip_bfloat16* __restrict__ d1,
    const float* __restrict__ s2, __hip_bfloat16* __restrict__ d2,
    const float* __restrict__ s3, __hip_bfloat16* __restrict__ d3,
    const float* __restrict__ te, const float* __restrict__ ce,
    const float* __restrict__ pe, const float* __restrict__ wfw,
    const float* __restrict__ wfb, const float* __restrict__ sw2,
    const float* __restrict__ sb2,
    float* __restrict__ TE2, float* __restrict__ CE2,
    float* __restrict__ PE2, float* __restrict__ WSPt,
    float* __restrict__ wfb2)
{
  int b = blockIdx.x, tid = threadIdx.x;
  if (b < 720) {
    const float* s; __hip_bfloat16* d; int base;
    if      (b < 324) { s = s0; d = d0; base = b; }
    else if (b < 432) { s = s1; d = d1; base = b - 324; }
    else if (b < 576) { s = s2; d = d2; base = b - 432; }
    else              { s = s3; d = d3; base = b - 576; }
    int i = (base * 256 + tid) * 8;
    float4 v0 = *(const float4*)(s + i);
    float4 v1 = *(const float4*)(s + i + 4);
    __hip_bfloat162* d2p = (__hip_bfloat162*)(d + i);
    d2p[0] = __float22bfloat162_rn(make_float2(v0.x, v0.y));
    d2p[1] = __float22bfloat162_rn(make_float2(v0.z, v0.w));
    d2p[2] = __float22bfloat162_rn(make_float2(v1.x, v1.y));
    d2p[3] = __float22bfloat162_rn(make_float2(v1.z, v1.w));
    return;
  }
  int blk = b - 720;
  if (blk < 1250) {
    int item = blk * 256 + tid;
    int v = item >> 7, o = item & 127;
    const float* src; float* dst; int base, vv;
    if (v < 1000)      { src = te; dst = TE2; base = 0;  vv = v; }
    else if (v < 1500) { src = ce; dst = CE2; base = 32; vv = v - 1000; }
    else               { src = pe; dst = PE2; base = 64; vv = v - 1500; }
    float a = 0.f;
    #pragma unroll 8
    for (int k = 0; k < 32; ++k) a += src[vv * 32 + k] * wfw[o * 128 + base + k];
    dst[vv * 128 + o] = a;
  } else if (blk < 1282) {
    int item = (blk - 1250) * 256 + tid;
    int j = item >> 7, o = item & 127;
    float a = 0.f;
    #pragma unroll 8
    for (int k = 0; k < 32; ++k) a += wfw[o * 128 + 96 + k] * sw2[k * 64 + j];
    WSPt[j * 128 + o] = a;
  } else if (tid < 128) {
    float a = wfb[tid];
    #pragma unroll 8
    for (int k = 0; k < 32; ++k) a += wfw[tid * 128 + 96 + k] * sb2[k];
    wfb2[tid] = a;
  }
}

// ---------------------------------------------------------------------------
// Encoder v5 (R10/R11-validated, 166us): 4 bs/block, wave <-> bs, lane owns
// cols {ln, ln+64}. Reverted verbatim after encode6 regression.
// ---------------------------------------------------------------------------
__global__ __launch_bounds__(256)
void encode5_kernel(
    const int* __restrict__ title_idx, const int* __restrict__ class_idx,
    const int* __restrict__ process_idx, const int* __restrict__ activity_type,
    const float* __restrict__ mouse_pos, const float* __restrict__ rect,
    const float* __restrict__ flags, const float* __restrict__ keyboard_active,
    const float* __restrict__ window_mask,
    const float* __restrict__ sw1, const float* __restrict__ sb1,
    const float* __restrict__ TE2, const float* __restrict__ CE2,
    const float* __restrict__ PE2, const float* __restrict__ WSPt,
    const float* __restrict__ wfb2,
    const float* __restrict__ mw1, const float* __restrict__ mb1,
    const float* __restrict__ mw2, const float* __restrict__ mb2,
    const float* __restrict__ act_emb, const float* __restrict__ kbw,
    const float* __restrict__ kbb,
    const float* __restrict__ afw, const float* __restrict__ afb,
    float* __restrict__ x, __hip_bfloat16* __restrict__ xb)
{
  __shared__ float h1all[4][20][64];
  __shared__ int   idxS[4][20][3];
  __shared__ float maskS[4][20];
  __shared__ float wfb2l[128];
  __shared__ float afA[4][68], afB[4][68];

  int tid = threadIdx.x;
  int w = tid >> 6, ln = tid & 63;
  int bs0 = blockIdx.x * 4;
  int bs = bs0 + w;

  if (tid < 128) wfb2l[tid] = wfb2[tid];
  for (int e = tid; e < 240; e += 256) {
    int g2 = e / 60, rem = e % 60, which = rem / 20, w_ = rem % 20;
    int rg = (bs0 + g2) * W_ + w_;
    const int* src = (which == 0) ? title_idx : (which == 1) ? class_idx : process_idx;
    idxS[g2][w_][which] = src[rg];
  }
  if (tid < 80) {
    int g2 = tid / 20, w_ = tid % 20;
    maskS[g2][w_] = window_mask[(bs0 + g2) * W_ + w_];
  }
  for (int e = tid; e < 5120; e += 256) {
    int g2 = e / 1280, rem = e - g2 * 1280;
    int w_ = rem >> 6, j = rem & 63;
    int rg = (bs0 + g2) * W_ + w_;
    float4 rc = *(const float4*)(rect + (size_t)rg * 4);
    float f0 = flags[rg * 2], f1 = flags[rg * 2 + 1];
    const float* w1 = sw1 + j * 6;
    float a = sb1[j] + w1[0]*rc.x + w1[1]*rc.y + w1[2]*rc.z + w1[3]*rc.w
                     + w1[4]*f0 + w1[5]*f1;
    h1all[g2][w_][j] = fmaxf(a, 0.f);
  }
  __syncthreads();

  float wsp0[64], wsp1[64];
  #pragma unroll
  for (int j = 0; j < 64; ++j) {
    wsp0[j] = WSPt[j * 128 + ln];
    wsp1[j] = WSPt[j * 128 + 64 + ln];
  }

  float acc0 = 0.f, acc1 = 0.f;
  for (int w_ = 0; w_ < W_; ++w_) {
    int t  = idxS[w][w_][0];
    int ci = idxS[w][w_][1];
    int p  = idxS[w][w_][2];
    float v0 = TE2[(size_t)t * 128 + ln] + CE2[(size_t)ci * 128 + ln]
             + PE2[(size_t)p * 128 + ln] + wfb2l[ln];
    float v1 = TE2[(size_t)t * 128 + 64 + ln] + CE2[(size_t)ci * 128 + 64 + ln]
             + PE2[(size_t)p * 128 + 64 + ln] + wfb2l[64 + ln];
    const float4* hp = (const float4*)&h1all[w][w_][0];
    #pragma unroll
    for (int j4 = 0; j4 < 16; ++j4) {
      float4 h = hp[j4];
      v0 += h.x*wsp0[4*j4] + h.y*wsp0[4*j4+1] + h.z*wsp0[4*j4+2] + h.w*wsp0[4*j4+3];
      v1 += h.x*wsp1[4*j4] + h.y*wsp1[4*j4+1] + h.z*wsp1[4*j4+2] + h.w*wsp1[4*j4+3];
    }
    float mk = maskS[w][w_];
    acc0 += fmaxf(v0, 0.f) * mk;
    acc1 += fmaxf(v1, 0.f) * mk;
  }
  {
    float v = acc0 * (1.f / (float)W_) + posenc(bs % S_, ln);
    x[(size_t)bs * D_ + ln] = v;
    xb[(size_t)bs * D_ + ln] = __float2bfloat16(v);
    v = acc1 * (1.f / (float)W_) + posenc(bs % S_, 64 + ln);
    x[(size_t)bs * D_ + 64 + ln] = v;
    xb[(size_t)bs * D_ + 64 + ln] = __float2bfloat16(v);
  }

  int bl = tid >> 6, ln63 = tid & 63;
  int bsg = bs0 + bl;
  __syncthreads();
  if (ln63 < 32) {
    float mx = mouse_pos[bsg * 2 + 0] * (1.f / 1920.f);
    float my = mouse_pos[bsg * 2 + 1] * (1.f / 1080.f);
    afA[bl][ln63] = fmaxf(mw1[ln63 * 2] * mx + mw1[ln63 * 2 + 1] * my + mb1[ln63], 0.f);
  }
  __syncthreads();
  float cv;
  if (ln63 < 32) {
    float a = mb2[ln63];
    #pragma unroll 8
    for (int k = 0; k < 32; ++k) a += mw2[ln63 * 32 + k] * afA[bl][k];
    cv = a;
  } else if (ln63 < 48) {
    cv = act_emb[activity_type[bsg] * 16 + (ln63 - 32)];
  } else {
    cv = kbw[ln63 - 48] * keyboard_active[bsg] + kbb[ln63 - 48];
  }
  __syncthreads();
  afB[bl][ln63] = cv;
  __syncthreads();
  {
    float a = afb[ln63];
    const float4* w4 = (const float4*)(afw + ln63 * 64);
    const float4* cp = (const float4*)&afB[bl][0];
    #pragma unroll
    for (int k4 = 0; k4 < 16; ++k4) {
      float4 ww = w4[k4], c2 = cp[k4];
      a += ww.x*c2.x + ww.y*c2.y + ww.z*c2.z + ww.w*c2.w;
    }
    float v = fmaxf(a, 0.f);
    int cg = 128 + ln63;
    float ovv = v + posenc(bsg % S_, cg);
    x[(size_t)bsg * D_ + cg] = ovv;
    xb[(size_t)bsg * D_ + cg] = __float2bfloat16(ovv);
  }
}

// ---------------------------------------------------------------------------
// Fused qkv + attention v2. One block per (b,h), 256 threads = 4 waves.
// R12 restructure: A (xb, full K=192) hoisted to LDS ONCE (pitch 200);
// B-frags read directly from global Wq (L2-hot, 16B/lane; garbage lanes
// m32>=24 only affect discarded output cols — dv guard). K-loop has ZERO
// barriers; kernel has 3 total (was 14).
// Arena 64000: Asl[0,51200) pitch 200 | Vt[55296,64000).
// Post-GEMM aliases: Qs[0,10240) Ks[10240,20480) Ps[20480,55296).
// Softmax/PV math identical to R7-validated version.
// ---------------------------------------------------------------------------
__global__ __launch_bounds__(256)
void qkvattn_kernel(const __hip_bfloat16* __restrict__ xb,
                    const __hip_bfloat16* __restrict__ Wq,
                    const float* __restrict__ qb,
                    __hip_bfloat16* __restrict__ o)
{
  __shared__ __align__(16) char smem[64000];
  __hip_bfloat16* Asl = (__hip_bfloat16*)smem;             // 128 x pitch200
  __hip_bfloat16* Qs  = (__hip_bfloat16*)smem;             // 128 x 40
  __hip_bfloat16* Ks  = (__hip_bfloat16*)(smem + 10240);   // 128 x 40
  __hip_bfloat16* Ps  = (__hip_bfloat16*)(smem + 20480);   // 128 x 136
  __hip_bfloat16* Vt  = (__hip_bfloat16*)(smem + 55296);   // 32 x 136

  int bh = blockIdx.x;
  int hh = bh & 7, b = bh >> 3;
  int tid = threadIdx.x, lane = tid & 63, w = tid >> 6;
  int m32 = lane & 31, half = lane >> 5;

  // zero Vt + stage full A (pitch 200, rows >= S replicate row S-1)
  for (int e = tid; e < (32 * 136) / 8; e += 256)
    ((float4*)Vt)[e] = make_float4(0.f, 0.f, 0.f, 0.f);
  for (int e = tid; e < 3072; e += 256) {
    int r = e / 24, seg = e - (e / 24) * 24;
    int rr = r < S_ ? r : S_ - 1;
    *(float4*)&Asl[r * 200 + seg * 8] =
        *(const float4*)&xb[(size_t)(b * S_ + rr) * D_ + seg * 8];
  }
  __syncthreads();                                   // barrier 1

  // ---- phase 1: qkv head-slice GEMM, barrier-free K-loop ----
  floatx16 acc[3];
  #pragma unroll
  for (int t = 0; t < 3; ++t)
    #pragma unroll
    for (int r = 0; r < 16; ++r) acc[t][r] = 0.f;

  #pragma unroll
  for (int k0 = 0; k0 < D_; k0 += 32) {
    #pragma unroll
    for (int kc = 0; kc < 2; ++kc) {
      int ko = k0 + kc * 16 + half * 8;
      short8 a = *(const short8*)&Asl[(w * 32 + m32) * 200 + ko];
      #pragma unroll
      for (int t = 0; t < 3; ++t) {
        short8 bf = *(const short8*)&Wq[(size_t)(t * D_ + hh * DH_ + m32) * D_ + ko];
        acc[t] = __builtin_amdgcn_mfma_f32_32x32x16_bf16(a, bf, acc[t], 0, 0, 0);
      }
    }
  }
  __syncthreads();                                   // barrier 2 (Asl dead)
  {
    bool dv = (m32 < DH_);
    float bq = dv ? qb[0 * D_ + hh * DH_ + m32] : 0.f;
    float bk = dv ? qb[1 * D_ + hh * DH_ + m32] : 0.f;
    float bv = dv ? qb[2 * D_ + hh * DH_ + m32] : 0.f;
    #pragma unroll
    for (int r = 0; r < 16; ++r) {
      int row = w * 32 + (r & 3) + 8 * (r >> 2) + 4 * half;
      Qs[row * 40 + m32] = __float2bfloat16(dv ? acc[0][r] + bq : 0.f);
      Ks[row * 40 + m32] = __float2bfloat16(dv ? acc[1][r] + bk : 0.f);
      if (dv) Vt[m32 * 136 + row] = __float2bfloat16(acc[2][r] + bv);
    }
  }
  __syncthreads();                                   // barrier 3

  // ---- phase 2: QK^T + softmax (validated) ----
  floatx16 sc[4];
  #pragma unroll
  for (int nt = 0; nt < 4; ++nt)
    #pragma unroll
    for (int r = 0; r < 16; ++r) sc[nt][r] = 0.f;
  #pragma unroll
  for (int kc = 0; kc < 2; ++kc) {
    int ko = kc * 16 + half * 8;
    short8 a = *(const short8*)&Qs[(w * 32 + m32) * 40 + ko];
    #pragma unroll
    for (int nt = 0; nt < 4; ++nt) {
      short8 bf = *(const short8*)&Ks[(nt * 32 + m32) * 40 + ko];
      sc[nt] = __builtin_amdgcn_mfma_f32_32x32x16_bf16(a, bf, sc[nt], 0, 0, 0);
    }
  }
  const float scale = 0.20412414523193154f;  // 1/sqrt(24)
  float rinv[16];
  #pragma unroll
  for (int r = 0; r < 16; ++r) {
    float mx = -1e30f;
    #pragma unroll
    for (int nt = 0; nt < 4; ++nt) {
      float s = sc[nt][r] * scale;
      if (nt == 3 && m32 >= 4) s = -1e30f;   // keys >= 100
      sc[nt][r] = s;
      mx = fmaxf(mx, s);
    }
    #pragma unroll
    for (int off = 1; off < 32; off <<= 1) mx = fmaxf(mx, __shfl_xor(mx, off));
    float sum = 0.f;
    #pragma unroll
    for (int nt = 0; nt < 4; ++nt) {
      float e = expf(sc[nt][r] - mx);
      sc[nt][r] = e;
      sum += e;
    }
    #pragma unroll
    for (int off = 1; off < 32; off <<= 1) sum += __shfl_xor(sum, off);
    rinv[r] = 1.f / sum;
  }
  #pragma unroll
  for (int r = 0; r < 16; ++r) {
    int rowl = (r & 3) + 8 * (r >> 2) + 4 * half;
    #pragma unroll
    for (int nt = 0; nt < 4; ++nt)
      Ps[(w * 32 + rowl) * 136 + nt * 32 + m32] = __float2bfloat16(sc[nt][r]);
  }
  // Ps wave-private, no alias with live Qs/Ks/Vt — no barrier.

  // ---- phase 3: PV (validated) ----
  floatx16 ov;
  #pragma unroll
  for (int r = 0; r < 16; ++r) ov[r] = 0.f;
  #pragma unroll
  for (int kt = 0; kt < 8; ++kt) {
    int ko = kt * 16 + half * 8;
    short8 a = *(const short8*)&Ps[(w * 32 + m32) * 136 + ko];
    short8 bf = *(const short8*)&Vt[m32 * 136 + ko];
    ov = __builtin_amdgcn_mfma_f32_32x32x16_bf16(a, bf, ov, 0, 0, 0);
  }
  #pragma unroll
  for (int r = 0; r < 16; ++r) {
    int rowl = (r & 3) + 8 * (r >> 2) + 4 * half;
    int q = w * 32 + rowl;
    if (m32 < DH_ && q < S_)
      o[((size_t)(b * S_ + q)) * D_ + hh * DH_ + m32] =
          __float2bfloat16(ov[r] * rinv[r]);
  }
}

// ---------------------------------------------------------------------------
// Fused out-proj+LN1 + ff1+ff2+LN2 (validated R10/R11). 200 blocks, 256 thr.
// ---------------------------------------------------------------------------
__global__ __launch_bounds__(256)
void outffln_kernel(const __hip_bfloat16* __restrict__ attb,
                    const __hip_bfloat16* __restrict__ Wo, const float* __restrict__ bo,
                    const float* __restrict__ g1, const float* __restrict__ b1v,
                    const __hip_bfloat16* __restrict__ W1, const float* __restrict__ b1,
                    const __hip_bfloat16* __restrict__ W2, const float* __restrict__ b2,
                    const float* __restrict__ g2, const float* __restrict__ b2v,
                    float* __restrict__ x, __hip_bfloat16* __restrict__ xb)
{
  __shared__ __align__(16) char arena[59904];
  __hip_bfloat16* AslA = (__hip_bfloat16*)arena;             // 64*40
  __hip_bfloat16* BslA = (__hip_bfloat16*)(arena + 5120);    // 192*40
  __hip_bfloat16* C1   = (__hip_bfloat16*)arena;             // 64*260
  __hip_bfloat16* AslB = (__hip_bfloat16*)(arena + 33280);   // 64*40
  __hip_bfloat16* BslB = (__hip_bfloat16*)(arena + 38400);   // 256*40
  float (*psum)[2] = (float(*)[2])(arena + 58880);
  float (*psq)[2]  = (float(*)[2])(arena + 59392);

  int tid = threadIdx.x, lane = tid & 63, w = tid >> 6;
  int m32 = lane & 31, half = lane >> 5;
  int mt = w & 1, ng = w >> 1;
  int bm = blockIdx.x * 64;

  // ========= phase A: out-proj + residual + LN1 =========
  floatx16 accA[3];
  #pragma unroll
  for (int j = 0; j < 3; ++j)
    #pragma unroll
    for (int r = 0; r < 16; ++r) accA[j][r] = 0.f;

  for (int k0 = 0; k0 < D_; k0 += 32) {
    if (tid < 128) {
      int r = tid >> 1, h = tid & 1;
      const float4* s = (const float4*)(attb + (size_t)(bm + r) * D_ + k0 + h * 16);
      float4* d = (float4*)&AslA[r * 40 + h * 16];
      d[0] = s[0]; d[1] = s[1];
    }
    for (int e = tid; e < 384; e += 256) {
      int r = e >> 1, h = e & 1;
      const float4* s = (const float4*)(Wo + (size_t)r * D_ + k0 + h * 16);
      float4* d = (float4*)&BslA[r * 40 + h * 16];
      d[0] = s[0]; d[1] = s[1];
    }
    __syncthreads();
    #pragma unroll
    for (int kc = 0; kc < 2; ++kc) {
      int ko = kc * 16 + half * 8;
      short8 a = *(const short8*)&AslA[(mt * 32 + m32) * 40 + ko];
      #pragma unroll
      for (int j = 0; j < 3; ++j) {
        short8 bf = *(const short8*)&BslA[((ng * 3 + j) * 32 + m32) * 40 + ko];
        accA[j] = __builtin_amdgcn_mfma_f32_32x32x16_bf16(a, bf, accA[j], 0, 0, 0);
      }
    }
    __syncthreads();
  }
  {
    int rowb = mt * 32 + 4 * half;
    #pragma unroll
    for (int r = 0; r < 16; ++r) {
      int rl = rowb + (r & 3) + 8 * (r >> 2);
      int row = bm + rl;
      float p = 0.f;
      #pragma unroll
      for (int j = 0; j < 3; ++j) {
        int col = (ng * 3 + j) * 32 + m32;
        float t = accA[j][r] + bo[col] + x[(size_t)row * D_ + col];
        accA[j][r] = t;
        p += t;
      }
      #pragma unroll
      for (int off = 1; off < 32; off <<= 1) p += __shfl_xor(p, off);
      if (m32 == 0) psum[rl][ng] = p;
    }
    __syncthreads();
    float mean[16];
    #pragma unroll
    for (int r = 0; r < 16; ++r) {
      int rl = rowb + (r & 3) + 8 * (r >> 2);
      mean[r] = (psum[rl][0] + psum[rl][1]) * (1.f / (float)D_);
    }
    #pragma unroll
    for (int r = 0; r < 16; ++r) {
      int rl = rowb + (r & 3) + 8 * (r >> 2);
      float s = 0.f;
      #pragma unroll
      for (int j = 0; j < 3; ++j) { float dd = accA[j][r] - mean[r]; s += dd * dd; }
      #pragma unroll
      for (int off = 1; off < 32; off <<= 1) s += __shfl_xor(s, off);
      if (m32 == 0) psq[rl][ng] = s;
    }
    __syncthreads();
    #pragma unroll
    for (int r = 0; r < 16; ++r) {
      int rl = rowb + (r & 3) + 8 * (r >> 2);
      int row = bm + rl;
      float inv = rsqrtf((psq[rl][0] + psq[rl][1]) * (1.f / (float)D_) + 1e-5f);
      #pragma unroll
      for (int j = 0; j < 3; ++j) {
        int col = (ng * 3 + j) * 32 + m32;
        float ovv = (accA[j][r] - mean[r]) * inv * g1[col] + b1v[col];
        x[(size_t)row * D_ + col] = ovv;
        xb[(size_t)row * D_ + col] = __float2bfloat16(ovv);
      }
    }
  }
  __syncthreads();

  // ========= phase B: ff1 + ff2 + residual + LN2 =========
  floatx16 acc1[4];
  #pragma unroll
  for (int j = 0; j < 4; ++j)
    #pragma unroll
    for (int r = 0; r < 16; ++r) acc1[j][r] = 0.f;

  for (int k0 = 0; k0 < D_; k0 += 32) {
    if (tid < 128) {
      int r = tid >> 1, h = tid & 1;
      const float4* s = (const float4*)(xb + (size_t)(bm + r) * D_ + k0 + h * 16);
      float4* d = (float4*)&AslB[r * 40 + h * 16];
      d[0] = s[0]; d[1] = s[1];
    }
    for (int e = tid; e < 512; e += 256) {
      int r = e >> 1, h = e & 1;
      const float4* s = (const float4*)(W1 + (size_t)r * D_ + k0 + h * 16);
      float4* d = (float4*)&BslB[r * 40 + h * 16];
      d[0] = s[0]; d[1] = s[1];
    }
    __syncthreads();
    #pragma unroll
    for (int kc = 0; kc < 2; ++kc) {
      int ko = kc * 16 + half * 8;
      short8 a = *(const short8*)&AslB[(mt * 32 + m32) * 40 + ko];
      #pragma unroll
      for (int j = 0; j < 4; ++j) {
        short8 bf = *(const short8*)&BslB[((ng * 4 + j) * 32 + m32) * 40 + ko];
        acc1[j] = __builtin_amdgcn_mfma_f32_32x32x16_bf16(a, bf, acc1[j], 0, 0, 0);
      }
    }
    __syncthreads();
  }
  {
    int rowb = mt * 32 + 4 * half;
    #pragma unroll
    for (int j = 0; j < 4; ++j) {
      int col = (ng * 4 + j) * 32 + m32;
      float cb = b1[col];
      #pragma unroll
      for (int r = 0; r < 16; ++r) {
        int row = rowb + (r & 3) + 8 * (r >> 2);
        C1[row * 260 + col] = __float2bfloat16(fmaxf(acc1[j][r] + cb, 0.f));
      }
    }
  }
  __syncthreads();

  floatx16 acc2[3];
  #pragma unroll
  for (int j = 0; j < 3; ++j)
    #pragma unroll
    for (int r = 0; r < 16; ++r) acc2[j][r] = 0.f;

  for (int k0 = 0; k0 < DFF_; k0 += 32) {
    for (int e = tid; e < 384; e += 256) {
      int r = e >> 1, h = e & 1;
      const float4* s = (const float4*)(W2 + (size_t)r * DFF_ + k0 + h * 16);
      float4* d = (float4*)&BslB[r * 40 + h * 16];
      d[0] = s[0]; d[1] = s[1];
    }
    __syncthreads();
    #pragma unroll
    for (int kc = 0; kc < 2; ++kc) {
      int ko = kc * 16 + half * 8;
      short8 a = ld_frag8(&C1[(mt * 32 + m32) * 260 + k0 + ko]);
      #pragma unroll
      for (int j = 0; j < 3; ++j) {
        short8 bf = *(const short8*)&BslB[((ng * 3 + j) * 32 + m32) * 40 + ko];
        acc2[j] = __builtin_amdgcn_mfma_f32_32x32x16_bf16(a, bf, acc2[j], 0, 0, 0);
      }
    }
    __syncthreads();
  }

  int rowb = mt * 32 + 4 * half;
  #pragma unroll
  for (int r = 0; r < 16; ++r) {
    int rl = rowb + (r & 3) + 8 * (r >> 2);
    int row = bm + rl;
    float p = 0.f;
    #pragma unroll
    for (int j = 0; j < 3; ++j) {
      int col = (ng * 3 + j) * 32 + m32;
      float t = acc2[j][r] + b2[col] + x[(size_t)row * D_ + col];
      acc2[j][r] = t;
      p += t;
    }
    #pragma unroll
    for (int off = 1; off < 32; off <<= 1) p += __shfl_xor(p, off);
    if (m32 == 0) psum[rl][ng] = p;
  }
  __syncthreads();
  float mean[16];
  #pragma unroll
  for (int r = 0; r < 16; ++r) {
    int rl = rowb + (r & 3) + 8 * (r >> 2);
    mean[r] = (psum[rl][0] + psum[rl][1]) * (1.f / (float)D_);
  }
  #pragma unroll
  for (int r = 0; r < 16; ++r) {
    int rl = rowb + (r & 3) + 8 * (r >> 2);
    float s = 0.f;
    #pragma unroll
    for (int j = 0; j < 3; ++j) { float dd = acc2[j][r] - mean[r]; s += dd * dd; }
    #pragma unroll
    for (int off = 1; off < 32; off <<= 1) s += __shfl_xor(s, off);
    if (m32 == 0) psq[rl][ng] = s;
  }
  __syncthreads();
  #pragma unroll
  for (int r = 0; r < 16; ++r) {
    int rl = rowb + (r & 3) + 8 * (r >> 2);
    int row = bm + rl;
    float inv = rsqrtf((psq[rl][0] + psq[rl][1]) * (1.f / (float)D_) + 1e-5f);
    #pragma unroll
    for (int j = 0; j < 3; ++j) {
      int col = (ng * 3 + j) * 32 + m32;
      float ovv = (acc2[j][r] - mean[r]) * inv * g2[col] + b2v[col];
      x[(size_t)row * D_ + col] = ovv;
      xb[(size_t)row * D_ + col] = __float2bfloat16(ovv);
    }
  }
}

// ---------------------------------------------------------------------------
// Head (fp32): one block per (w,b) slot.
// ---------------------------------------------------------------------------
__global__ __launch_bounds__(256)
void head_kernel(const float* __restrict__ x, const float* __restrict__ noise,
                 const float* __restrict__ pw1, const float* __restrict__ pb1,
                 const float* __restrict__ pw2, const float* __restrict__ pb2,
                 const float* __restrict__ ew1, const float* __restrict__ eb1,
                 const float* __restrict__ ew2, const float* __restrict__ eb2,
                 float* __restrict__ out)
{
  int idx = blockIdx.x;
  int b = idx & 127, w = idx >> 7;
  int tid = threadIdx.x;
  __shared__ float slot[192];
  __shared__ float ph[256];
  __shared__ float eh[128];
  if (tid < 192)
    slot[tid] = x[((size_t)b * S_ + (S_ - 1)) * D_ + tid]
              + noise[((size_t)w * B_ + b) * D_ + tid] * 0.1f;
  __syncthreads();
  {
    const float4* wr = (const float4*)(pw1 + (size_t)tid * D_);
    const float4* sp = (const float4*)slot;
    float a = pb1[tid];
    #pragma unroll 12
    for (int k = 0; k < 48; ++k) {
      float4 wv = wr[k], sv = sp[k];
      a += wv.x*sv.x + wv.y*sv.y + wv.z*sv.z + wv.w*sv.w;
    }
    ph[tid] = fmaxf(a, 0.f);
  }
  if (tid < 128) {
    const float4* wr = (const float4*)(ew1 + (size_t)tid * D_);
    const float4* sp = (const float4*)slot;
    float a = eb1[tid];
    #pragma unroll 12
    for (int k = 0; k < 48; ++k) {
      float4 wv = wr[k], sv = sp[k];
      a += wv.x*sv.x + wv.y*sv.y + wv.z*sv.z + wv.w*sv.w;
    }
    eh[tid] = fmaxf(a, 0.f);
  }
  __syncthreads();
  if (tid < 4) {
    float a = pb2[tid];
    const float4* wr = (const float4*)(pw2 + tid * 256);
    const float4* pp = (const float4*)ph;
    for (int k = 0; k < 64; ++k) {
      float4 wv = wr[k], pv = pp[k];
      a += wv.x*pv.x + wv.y*pv.y + wv.z*pv.z + wv.w*pv.w;
    }
    out[((size_t)b * W_ + w) * 4 + tid] = a;
  }
  if (tid == 4) {
    float a = eb2[0];
    const float4* wr = (const float4*)ew2;
    const float4* pp = (const float4*)eh;
    for (int k = 0; k < 32; ++k) {
      float4 wv = wr[k], pv = pp[k];
      a += wv.x*pv.x + wv.y*pv.y + wv.z*pv.z + wv.w*pv.w;
    }
    out[(size_t)B_ * W_ * 4 + (size_t)b * W_ + w] = 1.f / (1.f + expf(-a));
  }
}

// ---------------------------------------------------------------------------
extern "C" void kernel_launch(void* const* d_in, const int* in_sizes, int n_in,
                              void* d_out, int out_size, void* d_ws, size_t ws_size,
                              hipStream_t stream)
{
  const int*   title_idx       = (const int*)  d_in[0];
  const int*   class_idx       = (const int*)  d_in[1];
  const int*   process_idx     = (const int*)  d_in[2];
  const int*   activity_type   = (const int*)  d_in[3];
  const float* mouse_pos       = (const float*)d_in[4];
  const float* rect            = (const float*)d_in[5];
  const float* flags           = (const float*)d_in[6];
  const float* keyboard_active = (const float*)d_in[7];
  const float* window_mask     = (const float*)d_in[8];
  const float* noise           = (const float*)d_in[9];
  const float* title_emb       = (const float*)d_in[10];
  const float* class_emb       = (const float*)d_in[11];
  const float* process_emb     = (const float*)d_in[12];
  const float* spatial_w1      = (const float*)d_in[13];
  const float* spatial_b1      = (const float*)d_in[14];
  const float* spatial_w2      = (const float*)d_in[15];
  const float* spatial_b2      = (const float*)d_in[16];
  const float* wfuse_w         = (const float*)d_in[17];
  const float* wfuse_b         = (const float*)d_in[18];
  const float* mouse_w1        = (const float*)d_in[19];
  const float* mouse_b1        = (const float*)d_in[20];
  const float* mouse_w2        = (const float*)d_in[21];
  const float* mouse_b2        = (const float*)d_in[22];
  const float* act_emb         = (const float*)d_in[23];
  const float* kbd_w           = (const float*)d_in[24];
  const float* kbd_b           = (const float*)d_in[25];
  const float* afuse_w         = (const float*)d_in[26];
  const float* afuse_b         = (const float*)d_in[27];
  const float* qkv_w           = (const float*)d_in[28];
  const float* qkv_b           = (const float*)d_in[29];
  const float* out_w           = (const float*)d_in[30];
  const float* out_b           = (const float*)d_in[31];
  const float* ff1_w           = (const float*)d_in[32];
  const float* ff1_b           = (const float*)d_in[33];
  const float* ff2_w           = (const float*)d_in[34];
  const float* ff2_b           = (const float*)d_in[35];
  const float* ln1_g           = (const float*)d_in[36];
  const float* ln1_b           = (const float*)d_in[37];
  const float* ln2_g           = (const float*)d_in[38];
  const float* ln2_b           = (const float*)d_in[39];
  const float* proj_w1         = (const float*)d_in[40];
  const float* proj_b1         = (const float*)d_in[41];
  const float* proj_w2         = (const float*)d_in[42];
  const float* proj_b2         = (const float*)d_in[43];
  const float* ex_w1           = (const float*)d_in[44];
  const float* ex_b1           = (const float*)d_in[45];
  const float* ex_w2           = (const float*)d_in[46];
  const float* ex_b2           = (const float*)d_in[47];

  float* out = (float*)d_out;

  // workspace layout
  float* x = (float*)d_ws;                                      // BS*192 f32
  __hip_bfloat16* xb   = (__hip_bfloat16*)(x + (size_t)BS_ * D_);
  __hip_bfloat16* attb = xb   + (size_t)BS_ * D_;
  __hip_bfloat16* wqb  = attb + (size_t)BS_ * D_;
  __hip_bfloat16* wob  = wqb  + (size_t)L_ * THREED_ * D_;
  __hip_bfloat16* wf1b = wob  + (size_t)L_ * D_ * D_;
  __hip_bfloat16* wf2b = wf1b + (size_t)L_ * DFF_ * D_;
  float* TE2  = (float*)(wf2b + (size_t)L_ * D_ * DFF_);        // 1000*128
  float* CE2  = TE2  + 1000 * 128;                              // 500*128
  float* PE2  = CE2  + 500 * 128;                               // 1000*128
  float* WSPt = PE2  + 1000 * 128;                              // 64*128
  float* wfb2 = WSPt + 64 * 128;                                // 128
  (void)ws_size; (void)n_in; (void)in_sizes; (void)out_size;

  convertprep_kernel<<<2003, 256, 0, stream>>>(
      qkv_w, wqb, out_w, wob, ff1_w, wf1b, ff2_w, wf2b,
      title_emb, class_emb, process_emb, wfuse_w, wfuse_b,
      spatial_w2, spatial_b2, TE2, CE2, PE2, WSPt, wfb2);

  encode5_kernel<<<BS_ / 4, 256, 0, stream>>>(
      title_idx, class_idx, process_idx, activity_type, mouse_pos, rect, flags,
      keyboard_active, window_mask, spatial_w1, spatial_b1,
      TE2, CE2, PE2, WSPt, wfb2,
      mouse_w1, mouse_b1, mouse_w2, mouse_b2, act_emb, kbd_w, kbd_b,
      afuse_w, afuse_b, x, xb);

  for (int l = 0; l < L_; ++l) {
    qkvattn_kernel<<<B_ * H_, 256, 0, stream>>>(
        xb, wqb + (size_t)l * THREED_ * D_, qkv_b + (size_t)l * THREED_, attb);
    outffln_kernel<<<BS_ / 64, 256, 0, stream>>>(
        attb, wob + (size_t)l * D_ * D_, out_b + (size_t)l * D_,
        ln1_g + (size_t)l * D_, ln1_b + (size_t)l * D_,
        wf1b + (size_t)l * DFF_ * D_, ff1_b + (size_t)l * DFF_,
        wf2b + (size_t)l * D_ * DFF_, ff2_b + (size_t)l * D_,
        ln2_g + (size_t)l * D_, ln2_b + (size_t)l * D_, x, xb);
  }

  head_kernel<<<W_ * B_, 256, 0, stream>>>(
      x, noise, proj_w1, proj_b1, proj_w2, proj_b2,
      ex_w1, ex_b1, ex_w2, ex_b2, out);
}

// Round 14
// 838.272 us; speedup vs baseline: 1.1219x; 1.0873x over previous
//
#include <hip/hip_runtime.h>
#include <hip/hip_bf16.h>
#include <math.h>

#define B_ 128
#define S_ 100
#define W_ 20
#define D_ 192
#define L_ 6
#define H_ 8
#define DFF_ 256
#define DH_ 24
#define BS_ (B_*S_)
#define THREED_ 576

typedef short short8 __attribute__((ext_vector_type(8)));
typedef short short4v __attribute__((ext_vector_type(4)));
typedef float floatx16 __attribute__((ext_vector_type(16)));

__device__ __forceinline__ float posenc(int s, int c) {
  float freq = expf(-logf(10000.f) * (float)(2 * (c >> 1)) / (float)D_);
  float ang = (float)s * freq;
  return (c & 1) ? cosf(ang) : sinf(ang);
}

__device__ __forceinline__ short8 ld_frag8(const __hip_bfloat16* p) {
  short4v lo = *(const short4v*)p;
  short4v hi = *(const short4v*)(p + 4);
  short8 r;
  r[0]=lo[0]; r[1]=lo[1]; r[2]=lo[2]; r[3]=lo[3];
  r[4]=hi[0]; r[5]=hi[1]; r[6]=hi[2]; r[7]=hi[3];
  return r;
}

// ---------------------------------------------------------------------------
// Merged weight conversion + encoder precompute. 2003 blocks.
// R13: TE2/CE2/PE2 and wfb2 now PACKED as (col, col+64) float2 pairs:
//   table[v*128 + c*2 + 0] = fold(v, c)       (c in [0,64))
//   table[v*128 + c*2 + 1] = fold(v, c+64)
// so encode5's per-window gathers become one coalesced 8B load per table.
// ---------------------------------------------------------------------------
__global__ __launch_bounds__(256)
void convertprep_kernel(
    const float* __restrict__ s0, __hip_bfloat16* __restrict__ d0,
    const float* __restrict__ s1, __hip_bfloat16* __restrict__ d1,
    const float* __restrict__ s2, __hip_bfloat16* __restrict__ d2,
    const float* __restrict__ s3, __hip_bfloat16* __restrict__ d3,
    const float* __restrict__ te, const float* __restrict__ ce,
    const float* __restrict__ pe, const float* __restrict__ wfw,
    const float* __restrict__ wfb, const float* __restrict__ sw2,
    const float* __restrict__ sb2,
    float* __restrict__ TE2, float* __restrict__ CE2,
    float* __restrict__ PE2, float* __restrict__ WSPt,
    float* __restrict__ wfb2)
{
  int b = blockIdx.x, tid = threadIdx.x;
  if (b < 720) {
    const float* s; __hip_bfloat16* d; int base;
    if      (b < 324) { s = s0; d = d0; base = b; }
    else if (b < 432) { s = s1; d = d1; base = b - 324; }
    else if (b < 576) { s = s2; d = d2; base = b - 432; }
    else              { s = s3; d = d3; base = b - 576; }
    int i = (base * 256 + tid) * 8;
    float4 v0 = *(const float4*)(s + i);
    float4 v1 = *(const float4*)(s + i + 4);
    __hip_bfloat162* d2p = (__hip_bfloat162*)(d + i);
    d2p[0] = __float22bfloat162_rn(make_float2(v0.x, v0.y));
    d2p[1] = __float22bfloat162_rn(make_float2(v0.z, v0.w));
    d2p[2] = __float22bfloat162_rn(make_float2(v1.x, v1.y));
    d2p[3] = __float22bfloat162_rn(make_float2(v1.z, v1.w));
    return;
  }
  int blk = b - 720;
  if (blk < 1250) {
    int item = blk * 256 + tid;
    int v = item >> 7, o = item & 127;          // o = logical output col
    const float* src; float* dst; int base, vv;
    if (v < 1000)      { src = te; dst = TE2; base = 0;  vv = v; }
    else if (v < 1500) { src = ce; dst = CE2; base = 32; vv = v - 1000; }
    else               { src = pe; dst = PE2; base = 64; vv = v - 1500; }
    float a = 0.f;
    #pragma unroll 8
    for (int k = 0; k < 32; ++k) a += src[vv * 32 + k] * wfw[o * 128 + base + k];
    dst[vv * 128 + (o & 63) * 2 + (o >> 6)] = a;     // packed (c, c+64) pairs
  } else if (blk < 1282) {
    int item = (blk - 1250) * 256 + tid;
    int j = item >> 7, o = item & 127;
    float a = 0.f;
    #pragma unroll 8
    for (int k = 0; k < 32; ++k) a += wfw[o * 128 + 96 + k] * sw2[k * 64 + j];
    WSPt[j * 128 + o] = a;
  } else if (tid < 128) {
    float a = wfb[tid];
    #pragma unroll 8
    for (int k = 0; k < 32; ++k) a += wfw[tid * 128 + 96 + k] * sb2[k];
    wfb2[(tid & 63) * 2 + (tid >> 6)] = a;           // packed
  }
}

// ---------------------------------------------------------------------------
// Encoder v5p (validated 166us structure + packed-gather tables): 4 bs/block,
// wave <-> bs, lane owns cols {ln, ln+64}. Gathers: 3x 8B loads per window
// (was 6x 4B).
// ---------------------------------------------------------------------------
__global__ __launch_bounds__(256)
void encode5_kernel(
    const int* __restrict__ title_idx, const int* __restrict__ class_idx,
    const int* __restrict__ process_idx, const int* __restrict__ activity_type,
    const float* __restrict__ mouse_pos, const float* __restrict__ rect,
    const float* __restrict__ flags, const float* __restrict__ keyboard_active,
    const float* __restrict__ window_mask,
    const float* __restrict__ sw1, const float* __restrict__ sb1,
    const float* __restrict__ TE2, const float* __restrict__ CE2,
    const float* __restrict__ PE2, const float* __restrict__ WSPt,
    const float* __restrict__ wfb2,
    const float* __restrict__ mw1, const float* __restrict__ mb1,
    const float* __restrict__ mw2, const float* __restrict__ mb2,
    const float* __restrict__ act_emb, const float* __restrict__ kbw,
    const float* __restrict__ kbb,
    const float* __restrict__ afw, const float* __restrict__ afb,
    float* __restrict__ x, __hip_bfloat16* __restrict__ xb)
{
  __shared__ float h1all[4][20][64];
  __shared__ int   idxS[4][20][3];
  __shared__ float maskS[4][20];
  __shared__ float wfb2l[128];     // packed layout
  __shared__ float afA[4][68], afB[4][68];

  int tid = threadIdx.x;
  int w = tid >> 6, ln = tid & 63;
  int bs0 = blockIdx.x * 4;
  int bs = bs0 + w;

  if (tid < 128) wfb2l[tid] = wfb2[tid];
  for (int e = tid; e < 240; e += 256) {
    int g2 = e / 60, rem = e % 60, which = rem / 20, w_ = rem % 20;
    int rg = (bs0 + g2) * W_ + w_;
    const int* src = (which == 0) ? title_idx : (which == 1) ? class_idx : process_idx;
    idxS[g2][w_][which] = src[rg];
  }
  if (tid < 80) {
    int g2 = tid / 20, w_ = tid % 20;
    maskS[g2][w_] = window_mask[(bs0 + g2) * W_ + w_];
  }
  for (int e = tid; e < 5120; e += 256) {
    int g2 = e / 1280, rem = e - g2 * 1280;
    int w_ = rem >> 6, j = rem & 63;
    int rg = (bs0 + g2) * W_ + w_;
    float4 rc = *(const float4*)(rect + (size_t)rg * 4);
    float f0 = flags[rg * 2], f1 = flags[rg * 2 + 1];
    const float* w1 = sw1 + j * 6;
    float a = sb1[j] + w1[0]*rc.x + w1[1]*rc.y + w1[2]*rc.z + w1[3]*rc.w
                     + w1[4]*f0 + w1[5]*f1;
    h1all[g2][w_][j] = fmaxf(a, 0.f);
  }
  __syncthreads();

  float wsp0[64], wsp1[64];
  #pragma unroll
  for (int j = 0; j < 64; ++j) {
    wsp0[j] = WSPt[j * 128 + ln];
    wsp1[j] = WSPt[j * 128 + 64 + ln];
  }

  float wb0 = wfb2l[ln * 2], wb1 = wfb2l[ln * 2 + 1];
  float acc0 = 0.f, acc1 = 0.f;
  for (int w_ = 0; w_ < W_; ++w_) {
    int t  = idxS[w][w_][0];
    int ci = idxS[w][w_][1];
    int p  = idxS[w][w_][2];
    float2 gt = *(const float2*)&TE2[(size_t)t * 128 + ln * 2];
    float2 gc = *(const float2*)&CE2[(size_t)ci * 128 + ln * 2];
    float2 gp = *(const float2*)&PE2[(size_t)p * 128 + ln * 2];
    float v0 = gt.x + gc.x + gp.x + wb0;
    float v1 = gt.y + gc.y + gp.y + wb1;
    const float4* hp = (const float4*)&h1all[w][w_][0];
    #pragma unroll
    for (int j4 = 0; j4 < 16; ++j4) {
      float4 h = hp[j4];
      v0 += h.x*wsp0[4*j4] + h.y*wsp0[4*j4+1] + h.z*wsp0[4*j4+2] + h.w*wsp0[4*j4+3];
      v1 += h.x*wsp1[4*j4] + h.y*wsp1[4*j4+1] + h.z*wsp1[4*j4+2] + h.w*wsp1[4*j4+3];
    }
    float mk = maskS[w][w_];
    acc0 += fmaxf(v0, 0.f) * mk;
    acc1 += fmaxf(v1, 0.f) * mk;
  }
  {
    float v = acc0 * (1.f / (float)W_) + posenc(bs % S_, ln);
    x[(size_t)bs * D_ + ln] = v;
    xb[(size_t)bs * D_ + ln] = __float2bfloat16(v);
    v = acc1 * (1.f / (float)W_) + posenc(bs % S_, 64 + ln);
    x[(size_t)bs * D_ + 64 + ln] = v;
    xb[(size_t)bs * D_ + 64 + ln] = __float2bfloat16(v);
  }

  int bl = tid >> 6, ln63 = tid & 63;
  int bsg = bs0 + bl;
  __syncthreads();
  if (ln63 < 32) {
    float mx = mouse_pos[bsg * 2 + 0] * (1.f / 1920.f);
    float my = mouse_pos[bsg * 2 + 1] * (1.f / 1080.f);
    afA[bl][ln63] = fmaxf(mw1[ln63 * 2] * mx + mw1[ln63 * 2 + 1] * my + mb1[ln63], 0.f);
  }
  __syncthreads();
  float cv;
  if (ln63 < 32) {
    float a = mb2[ln63];
    #pragma unroll 8
    for (int k = 0; k < 32; ++k) a += mw2[ln63 * 32 + k] * afA[bl][k];
    cv = a;
  } else if (ln63 < 48) {
    cv = act_emb[activity_type[bsg] * 16 + (ln63 - 32)];
  } else {
    cv = kbw[ln63 - 48] * keyboard_active[bsg] + kbb[ln63 - 48];
  }
  __syncthreads();
  afB[bl][ln63] = cv;
  __syncthreads();
  {
    float a = afb[ln63];
    const float4* w4 = (const float4*)(afw + ln63 * 64);
    const float4* cp = (const float4*)&afB[bl][0];
    #pragma unroll
    for (int k4 = 0; k4 < 16; ++k4) {
      float4 ww = w4[k4], c2 = cp[k4];
      a += ww.x*c2.x + ww.y*c2.y + ww.z*c2.z + ww.w*c2.w;
    }
    float v = fmaxf(a, 0.f);
    int cg = 128 + ln63;
    float ovv = v + posenc(bsg % S_, cg);
    x[(size_t)bsg * D_ + cg] = ovv;
    xb[(size_t)bsg * D_ + cg] = __float2bfloat16(ovv);
  }
}

// ---------------------------------------------------------------------------
// Fused qkv + attention (R7-validated math; R11 Ps-alias arena, measured
// neutral-to-positive in R12 isolation). One block per (b,h), 256 threads.
// Arena 47104 B -> 3 blocks/CU. R12's global-B variant REVERTED (uncoalesced
// 16B/lane row-strided B reads regressed ~11us/layer).
// ---------------------------------------------------------------------------
__global__ __launch_bounds__(256)
void qkvattn_kernel(const __hip_bfloat16* __restrict__ xb,
                    const __hip_bfloat16* __restrict__ Wq,
                    const float* __restrict__ qb,
                    __hip_bfloat16* __restrict__ o)
{
  __shared__ __align__(16) char smem[47104];
  __hip_bfloat16* Asl = (__hip_bfloat16*)smem;             // 128*40
  __hip_bfloat16* Bsl = (__hip_bfloat16*)(smem + 10240);   // 96*40
  __hip_bfloat16* Qs  = (__hip_bfloat16*)(smem + 17920);   // 128*40
  __hip_bfloat16* Ks  = (__hip_bfloat16*)(smem + 28160);   // 128*40
  __hip_bfloat16* Vt  = (__hip_bfloat16*)(smem + 38400);   // 32*136
  __hip_bfloat16* Ps  = (__hip_bfloat16*)smem;             // 128*136 (post-QK^T)

  int bh = blockIdx.x;
  int hh = bh & 7, b = bh >> 3;
  int tid = threadIdx.x, lane = tid & 63, w = tid >> 6;
  int m32 = lane & 31, half = lane >> 5;

  for (int e = tid; e < (32 * 136) / 8; e += 256)
    ((float4*)Vt)[e] = make_float4(0.f, 0.f, 0.f, 0.f);

  floatx16 acc[3];
  #pragma unroll
  for (int t = 0; t < 3; ++t)
    #pragma unroll
    for (int r = 0; r < 16; ++r) acc[t][r] = 0.f;

  for (int k0 = 0; k0 < D_; k0 += 32) {
    {
      int r = tid >> 1, h2 = tid & 1;
      int rr = r < S_ ? r : S_ - 1;
      const float4* s = (const float4*)&xb[(size_t)(b * S_ + rr) * D_ + k0 + h2 * 16];
      float4* d = (float4*)&Asl[r * 40 + h2 * 16];
      d[0] = s[0]; d[1] = s[1];
    }
    if (tid < 192) {
      int r = tid >> 1, h2 = tid & 1;
      int t = r >> 5, j = r & 31;
      float4 v0 = make_float4(0.f, 0.f, 0.f, 0.f), v1 = v0;
      if (j < DH_) {
        const float4* s =
            (const float4*)&Wq[(size_t)(t * D_ + hh * DH_ + j) * D_ + k0 + h2 * 16];
        v0 = s[0]; v1 = s[1];
      }
      float4* d = (float4*)&Bsl[r * 40 + h2 * 16];
      d[0] = v0; d[1] = v1;
    }
    __syncthreads();
    #pragma unroll
    for (int kc = 0; kc < 2; ++kc) {
      int ko = kc * 16 + half * 8;
      short8 a = *(const short8*)&Asl[(w * 32 + m32) * 40 + ko];
      #pragma unroll
      for (int t = 0; t < 3; ++t) {
        short8 bf = *(const short8*)&Bsl[(t * 32 + m32) * 40 + ko];
        acc[t] = __builtin_amdgcn_mfma_f32_32x32x16_bf16(a, bf, acc[t], 0, 0, 0);
      }
    }
    __syncthreads();
  }
  {
    bool dv = (m32 < DH_);
    float bq = dv ? qb[0 * D_ + hh * DH_ + m32] : 0.f;
    float bk = dv ? qb[1 * D_ + hh * DH_ + m32] : 0.f;
    float bv = dv ? qb[2 * D_ + hh * DH_ + m32] : 0.f;
    #pragma unroll
    for (int r = 0; r < 16; ++r) {
      int row = w * 32 + (r & 3) + 8 * (r >> 2) + 4 * half;
      Qs[row * 40 + m32] = __float2bfloat16(dv ? acc[0][r] + bq : 0.f);
      Ks[row * 40 + m32] = __float2bfloat16(dv ? acc[1][r] + bk : 0.f);
      if (dv) Vt[m32 * 136 + row] = __float2bfloat16(acc[2][r] + bv);
    }
  }
  __syncthreads();

  floatx16 sc[4];
  #pragma unroll
  for (int nt = 0; nt < 4; ++nt)
    #pragma unroll
    for (int r = 0; r < 16; ++r) sc[nt][r] = 0.f;
  #pragma unroll
  for (int kc = 0; kc < 2; ++kc) {
    int ko = kc * 16 + half * 8;
    short8 a = *(const short8*)&Qs[(w * 32 + m32) * 40 + ko];
    #pragma unroll
    for (int nt = 0; nt < 4; ++nt) {
      short8 bf = *(const short8*)&Ks[(nt * 32 + m32) * 40 + ko];
      sc[nt] = __builtin_amdgcn_mfma_f32_32x32x16_bf16(a, bf, sc[nt], 0, 0, 0);
    }
  }
  __syncthreads();   // all waves done reading Qs/Ks before Ps overwrites them

  const float scale = 0.20412414523193154f;  // 1/sqrt(24)
  float rinv[16];
  #pragma unroll
  for (int r = 0; r < 16; ++r) {
    float mx = -1e30f;
    #pragma unroll
    for (int nt = 0; nt < 4; ++nt) {
      float s = sc[nt][r] * scale;
      if (nt == 3 && m32 >= 4) s = -1e30f;   // keys >= 100
      sc[nt][r] = s;
      mx = fmaxf(mx, s);
    }
    #pragma unroll
    for (int off = 1; off < 32; off <<= 1) mx = fmaxf(mx, __shfl_xor(mx, off));
    float sum = 0.f;
    #pragma unroll
    for (int nt = 0; nt < 4; ++nt) {
      float e = expf(sc[nt][r] - mx);
      sc[nt][r] = e;
      sum += e;
    }
    #pragma unroll
    for (int off = 1; off < 32; off <<= 1) sum += __shfl_xor(sum, off);
    rinv[r] = 1.f / sum;
  }
  #pragma unroll
  for (int r = 0; r < 16; ++r) {
    int rowl = (r & 3) + 8 * (r >> 2) + 4 * half;
    #pragma unroll
    for (int nt = 0; nt < 4; ++nt)
      Ps[(w * 32 + rowl) * 136 + nt * 32 + m32] = __float2bfloat16(sc[nt][r]);
  }
  // Ps is wave-private — no barrier.

  floatx16 ov;
  #pragma unroll
  for (int r = 0; r < 16; ++r) ov[r] = 0.f;
  #pragma unroll
  for (int kt = 0; kt < 8; ++kt) {
    int ko = kt * 16 + half * 8;
    short8 a = *(const short8*)&Ps[(w * 32 + m32) * 136 + ko];
    short8 bf = *(const short8*)&Vt[m32 * 136 + ko];
    ov = __builtin_amdgcn_mfma_f32_32x32x16_bf16(a, bf, ov, 0, 0, 0);
  }
  #pragma unroll
  for (int r = 0; r < 16; ++r) {
    int rowl = (r & 3) + 8 * (r >> 2) + 4 * half;
    int q = w * 32 + rowl;
    if (m32 < DH_ && q < S_)
      o[((size_t)(b * S_ + q)) * D_ + hh * DH_ + m32] =
          __float2bfloat16(ov[r] * rinv[r]);
  }
}

// ---------------------------------------------------------------------------
// Fused out-proj+LN1 + ff1+ff2+LN2 (validated R10-R12). 200 blocks, 256 thr.
// ---------------------------------------------------------------------------
__global__ __launch_bounds__(256)
void outffln_kernel(const __hip_bfloat16* __restrict__ attb,
                    const __hip_bfloat16* __restrict__ Wo, const float* __restrict__ bo,
                    const float* __restrict__ g1, const float* __restrict__ b1v,
                    const __hip_bfloat16* __restrict__ W1, const float* __restrict__ b1,
                    const __hip_bfloat16* __restrict__ W2, const float* __restrict__ b2,
                    const float* __restrict__ g2, const float* __restrict__ b2v,
                    float* __restrict__ x, __hip_bfloat16* __restrict__ xb)
{
  __shared__ __align__(16) char arena[59904];
  __hip_bfloat16* AslA = (__hip_bfloat16*)arena;             // 64*40
  __hip_bfloat16* BslA = (__hip_bfloat16*)(arena + 5120);    // 192*40
  __hip_bfloat16* C1   = (__hip_bfloat16*)arena;             // 64*260
  __hip_bfloat16* AslB = (__hip_bfloat16*)(arena + 33280);   // 64*40
  __hip_bfloat16* BslB = (__hip_bfloat16*)(arena + 38400);   // 256*40
  float (*psum)[2] = (float(*)[2])(arena + 58880);
  float (*psq)[2]  = (float(*)[2])(arena + 59392);

  int tid = threadIdx.x, lane = tid & 63, w = tid >> 6;
  int m32 = lane & 31, half = lane >> 5;
  int mt = w & 1, ng = w >> 1;
  int bm = blockIdx.x * 64;

  // ========= phase A: out-proj + residual + LN1 =========
  floatx16 accA[3];
  #pragma unroll
  for (int j = 0; j < 3; ++j)
    #pragma unroll
    for (int r = 0; r < 16; ++r) accA[j][r] = 0.f;

  for (int k0 = 0; k0 < D_; k0 += 32) {
    if (tid < 128) {
      int r = tid >> 1, h = tid & 1;
      const float4* s = (const float4*)(attb + (size_t)(bm + r) * D_ + k0 + h * 16);
      float4* d = (float4*)&AslA[r * 40 + h * 16];
      d[0] = s[0]; d[1] = s[1];
    }
    for (int e = tid; e < 384; e += 256) {
      int r = e >> 1, h = e & 1;
      const float4* s = (const float4*)(Wo + (size_t)r * D_ + k0 + h * 16);
      float4* d = (float4*)&BslA[r * 40 + h * 16];
      d[0] = s[0]; d[1] = s[1];
    }
    __syncthreads();
    #pragma unroll
    for (int kc = 0; kc < 2; ++kc) {
      int ko = kc * 16 + half * 8;
      short8 a = *(const short8*)&AslA[(mt * 32 + m32) * 40 + ko];
      #pragma unroll
      for (int j = 0; j < 3; ++j) {
        short8 bf = *(const short8*)&BslA[((ng * 3 + j) * 32 + m32) * 40 + ko];
        accA[j] = __builtin_amdgcn_mfma_f32_32x32x16_bf16(a, bf, accA[j], 0, 0, 0);
      }
    }
    __syncthreads();
  }
  {
    int rowb = mt * 32 + 4 * half;
    #pragma unroll
    for (int r = 0; r < 16; ++r) {
      int rl = rowb + (r & 3) + 8 * (r >> 2);
      int row = bm + rl;
      float p = 0.f;
      #pragma unroll
      for (int j = 0; j < 3; ++j) {
        int col = (ng * 3 + j) * 32 + m32;
        float t = accA[j][r] + bo[col] + x[(size_t)row * D_ + col];
        accA[j][r] = t;
        p += t;
      }
      #pragma unroll
      for (int off = 1; off < 32; off <<= 1) p += __shfl_xor(p, off);
      if (m32 == 0) psum[rl][ng] = p;
    }
    __syncthreads();
    float mean[16];
    #pragma unroll
    for (int r = 0; r < 16; ++r) {
      int rl = rowb + (r & 3) + 8 * (r >> 2);
      mean[r] = (psum[rl][0] + psum[rl][1]) * (1.f / (float)D_);
    }
    #pragma unroll
    for (int r = 0; r < 16; ++r) {
      int rl = rowb + (r & 3) + 8 * (r >> 2);
      float s = 0.f;
      #pragma unroll
      for (int j = 0; j < 3; ++j) { float dd = accA[j][r] - mean[r]; s += dd * dd; }
      #pragma unroll
      for (int off = 1; off < 32; off <<= 1) s += __shfl_xor(s, off);
      if (m32 == 0) psq[rl][ng] = s;
    }
    __syncthreads();
    #pragma unroll
    for (int r = 0; r < 16; ++r) {
      int rl = rowb + (r & 3) + 8 * (r >> 2);
      int row = bm + rl;
      float inv = rsqrtf((psq[rl][0] + psq[rl][1]) * (1.f / (float)D_) + 1e-5f);
      #pragma unroll
      for (int j = 0; j < 3; ++j) {
        int col = (ng * 3 + j) * 32 + m32;
        float ovv = (accA[j][r] - mean[r]) * inv * g1[col] + b1v[col];
        x[(size_t)row * D_ + col] = ovv;
        xb[(size_t)row * D_ + col] = __float2bfloat16(ovv);
      }
    }
  }
  __syncthreads();

  // ========= phase B: ff1 + ff2 + residual + LN2 =========
  floatx16 acc1[4];
  #pragma unroll
  for (int j = 0; j < 4; ++j)
    #pragma unroll
    for (int r = 0; r < 16; ++r) acc1[j][r] = 0.f;

  for (int k0 = 0; k0 < D_; k0 += 32) {
    if (tid < 128) {
      int r = tid >> 1, h = tid & 1;
      const float4* s = (const float4*)(xb + (size_t)(bm + r) * D_ + k0 + h * 16);
      float4* d = (float4*)&AslB[r * 40 + h * 16];
      d[0] = s[0]; d[1] = s[1];
    }
    for (int e = tid; e < 512; e += 256) {
      int r = e >> 1, h = e & 1;
      const float4* s = (const float4*)(W1 + (size_t)r * D_ + k0 + h * 16);
      float4* d = (float4*)&BslB[r * 40 + h * 16];
      d[0] = s[0]; d[1] = s[1];
    }
    __syncthreads();
    #pragma unroll
    for (int kc = 0; kc < 2; ++kc) {
      int ko = kc * 16 + half * 8;
      short8 a = *(const short8*)&AslB[(mt * 32 + m32) * 40 + ko];
      #pragma unroll
      for (int j = 0; j < 4; ++j) {
        short8 bf = *(const short8*)&BslB[((ng * 4 + j) * 32 + m32) * 40 + ko];
        acc1[j] = __builtin_amdgcn_mfma_f32_32x32x16_bf16(a, bf, acc1[j], 0, 0, 0);
      }
    }
    __syncthreads();
  }
  {
    int rowb = mt * 32 + 4 * half;
    #pragma unroll
    for (int j = 0; j < 4; ++j) {
      int col = (ng * 4 + j) * 32 + m32;
      float cb = b1[col];
      #pragma unroll
      for (int r = 0; r < 16; ++r) {
        int row = rowb + (r & 3) + 8 * (r >> 2);
        C1[row * 260 + col] = __float2bfloat16(fmaxf(acc1[j][r] + cb, 0.f));
      }
    }
  }
  __syncthreads();

  floatx16 acc2[3];
  #pragma unroll
  for (int j = 0; j < 3; ++j)
    #pragma unroll
    for (int r = 0; r < 16; ++r) acc2[j][r] = 0.f;

  for (int k0 = 0; k0 < DFF_; k0 += 32) {
    for (int e = tid; e < 384; e += 256) {
      int r = e >> 1, h = e & 1;
      const float4* s = (const float4*)(W2 + (size_t)r * DFF_ + k0 + h * 16);
      float4* d = (float4*)&BslB[r * 40 + h * 16];
      d[0] = s[0]; d[1] = s[1];
    }
    __syncthreads();
    #pragma unroll
    for (int kc = 0; kc < 2; ++kc) {
      int ko = kc * 16 + half * 8;
      short8 a = ld_frag8(&C1[(mt * 32 + m32) * 260 + k0 + ko]);
      #pragma unroll
      for (int j = 0; j < 3; ++j) {
        short8 bf = *(const short8*)&BslB[((ng * 3 + j) * 32 + m32) * 40 + ko];
        acc2[j] = __builtin_amdgcn_mfma_f32_32x32x16_bf16(a, bf, acc2[j], 0, 0, 0);
      }
    }
    __syncthreads();
  }

  int rowb = mt * 32 + 4 * half;
  #pragma unroll
  for (int r = 0; r < 16; ++r) {
    int rl = rowb + (r & 3) + 8 * (r >> 2);
    int row = bm + rl;
    float p = 0.f;
    #pragma unroll
    for (int j = 0; j < 3; ++j) {
      int col = (ng * 3 + j) * 32 + m32;
      float t = acc2[j][r] + b2[col] + x[(size_t)row * D_ + col];
      acc2[j][r] = t;
      p += t;
    }
    #pragma unroll
    for (int off = 1; off < 32; off <<= 1) p += __shfl_xor(p, off);
    if (m32 == 0) psum[rl][ng] = p;
  }
  __syncthreads();
  float mean[16];
  #pragma unroll
  for (int r = 0; r < 16; ++r) {
    int rl = rowb + (r & 3) + 8 * (r >> 2);
    mean[r] = (psum[rl][0] + psum[rl][1]) * (1.f / (float)D_);
  }
  #pragma unroll
  for (int r = 0; r < 16; ++r) {
    int rl = rowb + (r & 3) + 8 * (r >> 2);
    float s = 0.f;
    #pragma unroll
    for (int j = 0; j < 3; ++j) { float dd = acc2[j][r] - mean[r]; s += dd * dd; }
    #pragma unroll
    for (int off = 1; off < 32; off <<= 1) s += __shfl_xor(s, off);
    if (m32 == 0) psq[rl][ng] = s;
  }
  __syncthreads();
  #pragma unroll
  for (int r = 0; r < 16; ++r) {
    int rl = rowb + (r & 3) + 8 * (r >> 2);
    int row = bm + rl;
    float inv = rsqrtf((psq[rl][0] + psq[rl][1]) * (1.f / (float)D_) + 1e-5f);
    #pragma unroll
    for (int j = 0; j < 3; ++j) {
      int col = (ng * 3 + j) * 32 + m32;
      float ovv = (acc2[j][r] - mean[r]) * inv * g2[col] + b2v[col];
      x[(size_t)row * D_ + col] = ovv;
      xb[(size_t)row * D_ + col] = __float2bfloat16(ovv);
    }
  }
}

// ---------------------------------------------------------------------------
// Head (fp32): one block per (w,b) slot.
// ---------------------------------------------------------------------------
__global__ __launch_bounds__(256)
void head_kernel(const float* __restrict__ x, const float* __restrict__ noise,
                 const float* __restrict__ pw1, const float* __restrict__ pb1,
                 const float* __restrict__ pw2, const float* __restrict__ pb2,
                 const float* __restrict__ ew1, const float* __restrict__ eb1,
                 const float* __restrict__ ew2, const float* __restrict__ eb2,
                 float* __restrict__ out)
{
  int idx = blockIdx.x;
  int b = idx & 127, w = idx >> 7;
  int tid = threadIdx.x;
  __shared__ float slot[192];
  __shared__ float ph[256];
  __shared__ float eh[128];
  if (tid < 192)
    slot[tid] = x[((size_t)b * S_ + (S_ - 1)) * D_ + tid]
              + noise[((size_t)w * B_ + b) * D_ + tid] * 0.1f;
  __syncthreads();
  {
    const float4* wr = (const float4*)(pw1 + (size_t)tid * D_);
    const float4* sp = (const float4*)slot;
    float a = pb1[tid];
    #pragma unroll 12
    for (int k = 0; k < 48; ++k) {
      float4 wv = wr[k], sv = sp[k];
      a += wv.x*sv.x + wv.y*sv.y + wv.z*sv.z + wv.w*sv.w;
    }
    ph[tid] = fmaxf(a, 0.f);
  }
  if (tid < 128) {
    const float4* wr = (const float4*)(ew1 + (size_t)tid * D_);
    const float4* sp = (const float4*)slot;
    float a = eb1[tid];
    #pragma unroll 12
    for (int k = 0; k < 48; ++k) {
      float4 wv = wr[k], sv = sp[k];
      a += wv.x*sv.x + wv.y*sv.y + wv.z*sv.z + wv.w*sv.w;
    }
    eh[tid] = fmaxf(a, 0.f);
  }
  __syncthreads();
  if (tid < 4) {
    float a = pb2[tid];
    const float4* wr = (const float4*)(pw2 + tid * 256);
    const float4* pp = (const float4*)ph;
    for (int k = 0; k < 64; ++k) {
      float4 wv = wr[k], pv = pp[k];
      a += wv.x*pv.x + wv.y*pv.y + wv.z*pv.z + wv.w*pv.w;
    }
    out[((size_t)b * W_ + w) * 4 + tid] = a;
  }
  if (tid == 4) {
    float a = eb2[0];
    const float4* wr = (const float4*)ew2;
    const float4* pp = (const float4*)eh;
    for (int k = 0; k < 32; ++k) {
      float4 wv = wr[k], pv = pp[k];
      a += wv.x*pv.x + wv.y*pv.y + wv.z*pv.z + wv.w*pv.w;
    }
    out[(size_t)B_ * W_ * 4 + (size_t)b * W_ + w] = 1.f / (1.f + expf(-a));
  }
}

// ---------------------------------------------------------------------------
extern "C" void kernel_launch(void* const* d_in, const int* in_sizes, int n_in,
                              void* d_out, int out_size, void* d_ws, size_t ws_size,
                              hipStream_t stream)
{
  const int*   title_idx       = (const int*)  d_in[0];
  const int*   class_idx       = (const int*)  d_in[1];
  const int*   process_idx     = (const int*)  d_in[2];
  const int*   activity_type   = (const int*)  d_in[3];
  const float* mouse_pos       = (const float*)d_in[4];
  const float* rect            = (const float*)d_in[5];
  const float* flags           = (const float*)d_in[6];
  const float* keyboard_active = (const float*)d_in[7];
  const float* window_mask     = (const float*)d_in[8];
  const float* noise           = (const float*)d_in[9];
  const float* title_emb       = (const float*)d_in[10];
  const float* class_emb       = (const float*)d_in[11];
  const float* process_emb     = (const float*)d_in[12];
  const float* spatial_w1      = (const float*)d_in[13];
  const float* spatial_b1      = (const float*)d_in[14];
  const float* spatial_w2      = (const float*)d_in[15];
  const float* spatial_b2      = (const float*)d_in[16];
  const float* wfuse_w         = (const float*)d_in[17];
  const float* wfuse_b         = (const float*)d_in[18];
  const float* mouse_w1        = (const float*)d_in[19];
  const float* mouse_b1        = (const float*)d_in[20];
  const float* mouse_w2        = (const float*)d_in[21];
  const float* mouse_b2        = (const float*)d_in[22];
  const float* act_emb         = (const float*)d_in[23];
  const float* kbd_w           = (const float*)d_in[24];
  const float* kbd_b           = (const float*)d_in[25];
  const float* afuse_w         = (const float*)d_in[26];
  const float* afuse_b         = (const float*)d_in[27];
  const float* qkv_w           = (const float*)d_in[28];
  const float* qkv_b           = (const float*)d_in[29];
  const float* out_w           = (const float*)d_in[30];
  const float* out_b           = (const float*)d_in[31];
  const float* ff1_w           = (const float*)d_in[32];
  const float* ff1_b           = (const float*)d_in[33];
  const float* ff2_w           = (const float*)d_in[34];
  const float* ff2_b           = (const float*)d_in[35];
  const float* ln1_g           = (const float*)d_in[36];
  const float* ln1_b           = (const float*)d_in[37];
  const float* ln2_g           = (const float*)d_in[38];
  const float* ln2_b           = (const float*)d_in[39];
  const float* proj_w1         = (const float*)d_in[40];
  const float* proj_b1         = (const float*)d_in[41];
  const float* proj_w2         = (const float*)d_in[42];
  const float* proj_b2         = (const float*)d_in[43];
  const float* ex_w1           = (const float*)d_in[44];
  const float* ex_b1           = (const float*)d_in[45];
  const float* ex_w2           = (const float*)d_in[46];
  const float* ex_b2           = (const float*)d_in[47];

  float* out = (float*)d_out;

  // workspace layout
  float* x = (float*)d_ws;                                      // BS*192 f32
  __hip_bfloat16* xb   = (__hip_bfloat16*)(x + (size_t)BS_ * D_);
  __hip_bfloat16* attb = xb   + (size_t)BS_ * D_;
  __hip_bfloat16* wqb  = attb + (size_t)BS_ * D_;
  __hip_bfloat16* wob  = wqb  + (size_t)L_ * THREED_ * D_;
  __hip_bfloat16* wf1b = wob  + (size_t)L_ * D_ * D_;
  __hip_bfloat16* wf2b = wf1b + (size_t)L_ * DFF_ * D_;
  float* TE2  = (float*)(wf2b + (size_t)L_ * D_ * DFF_);        // 1000*128
  float* CE2  = TE2  + 1000 * 128;                              // 500*128
  float* PE2  = CE2  + 500 * 128;                               // 1000*128
  float* WSPt = PE2  + 1000 * 128;                              // 64*128
  float* wfb2 = WSPt + 64 * 128;                                // 128
  (void)ws_size; (void)n_in; (void)in_sizes; (void)out_size;

  convertprep_kernel<<<2003, 256, 0, stream>>>(
      qkv_w, wqb, out_w, wob, ff1_w, wf1b, ff2_w, wf2b,
      title_emb, class_emb, process_emb, wfuse_w, wfuse_b,
      spatial_w2, spatial_b2, TE2, CE2, PE2, WSPt, wfb2);

  encode5_kernel<<<BS_ / 4, 256, 0, stream>>>(
      title_idx, class_idx, process_idx, activity_type, mouse_pos, rect, flags,
      keyboard_active, window_mask, spatial_w1, spatial_b1,
      TE2, CE2, PE2, WSPt, wfb2,
      mouse_w1, mouse_b1, mouse_w2, mouse_b2, act_emb, kbd_w, kbd_b,
      afuse_w, afuse_b, x, xb);

  for (int l = 0; l < L_; ++l) {
    qkvattn_kernel<<<B_ * H_, 256, 0, stream>>>(
        xb, wqb + (size_t)l * THREED_ * D_, qkv_b + (size_t)l * THREED_, attb);
    outffln_kernel<<<BS_ / 64, 256, 0, stream>>>(
        attb, wob + (size_t)l * D_ * D_, out_b + (size_t)l * D_,
        ln1_g + (size_t)l * D_, ln1_b + (size_t)l * D_,
        wf1b + (size_t)l * DFF_ * D_, ff1_b + (size_t)l * DFF_,
        wf2b + (size_t)l * D_ * DFF_, ff2_b + (size_t)l * D_,
        ln2_g + (size_t)l * D_, ln2_b + (size_t)l * D_, x, xb);
  }

  head_kernel<<<W_ * B_, 256, 0, stream>>>(
      x, noise, proj_w1, proj_b1, proj_w2, proj_b2,
      ex_w1, ex_b1, ex_w2, ex_b2, out);
}

// Round 16
// 835.773 us; speedup vs baseline: 1.1253x; 1.0030x over previous
//
#include <hip/hip_runtime.h>
#include <hip/hip_bf16.h>
#include <math.h>

#define B_ 128
#define S_ 100
#define W_ 20
#define D_ 192
#define L_ 6
#define H_ 8
#define DFF_ 256
#define DH_ 24
#define BS_ (B_*S_)
#define THREED_ 576

typedef short short8 __attribute__((ext_vector_type(8)));
typedef short short4v __attribute__((ext_vector_type(4)));
typedef float floatx16 __attribute__((ext_vector_type(16)));

__device__ __forceinline__ float posenc(int s, int c) {
  float freq = expf(-logf(10000.f) * (float)(2 * (c >> 1)) / (float)D_);
  float ang = (float)s * freq;
  return (c & 1) ? cosf(ang) : sinf(ang);
}

__device__ __forceinline__ short8 ld_frag8(const __hip_bfloat16* p) {
  short4v lo = *(const short4v*)p;
  short4v hi = *(const short4v*)(p + 4);
  short8 r;
  r[0]=lo[0]; r[1]=lo[1]; r[2]=lo[2]; r[3]=lo[3];
  r[4]=hi[0]; r[5]=hi[1]; r[6]=hi[2]; r[7]=hi[3];
  return r;
}

// ---------------------------------------------------------------------------
// Merged weight conversion + encoder precompute (R13-validated). 2003 blocks.
// TE2/CE2/PE2/wfb2 packed as (col, col+64) float2 pairs.
// ---------------------------------------------------------------------------
__global__ __launch_bounds__(256)
void convertprep_kernel(
    const float* __restrict__ s0, __hip_bfloat16* __restrict__ d0,
    const float* __restrict__ s1, __hip_bfloat16* __restrict__ d1,
    const float* __restrict__ s2, __hip_bfloat16* __restrict__ d2,
    const float* __restrict__ s3, __hip_bfloat16* __restrict__ d3,
    const float* __restrict__ te, const float* __restrict__ ce,
    const float* __restrict__ pe, const float* __restrict__ wfw,
    const float* __restrict__ wfb, const float* __restrict__ sw2,
    const float* __restrict__ sb2,
    float* __restrict__ TE2, float* __restrict__ CE2,
    float* __restrict__ PE2, float* __restrict__ WSPt,
    float* __restrict__ wfb2)
{
  int b = blockIdx.x, tid = threadIdx.x;
  if (b < 720) {
    const float* s; __hip_bfloat16* d; int base;
    if      (b < 324) { s = s0; d = d0; base = b; }
    else if (b < 432) { s = s1; d = d1; base = b - 324; }
    else if (b < 576) { s = s2; d = d2; base = b - 432; }
    else              { s = s3; d = d3; base = b - 576; }
    int i = (base * 256 + tid) * 8;
    float4 v0 = *(const float4*)(s + i);
    float4 v1 = *(const float4*)(s + i + 4);
    __hip_bfloat162* d2p = (__hip_bfloat162*)(d + i);
    d2p[0] = __float22bfloat162_rn(make_float2(v0.x, v0.y));
    d2p[1] = __float22bfloat162_rn(make_float2(v0.z, v0.w));
    d2p[2] = __float22bfloat162_rn(make_float2(v1.x, v1.y));
    d2p[3] = __float22bfloat162_rn(make_float2(v1.z, v1.w));
    return;
  }
  int blk = b - 720;
  if (blk < 1250) {
    int item = blk * 256 + tid;
    int v = item >> 7, o = item & 127;
    const float* src; float* dst; int base, vv;
    if (v < 1000)      { src = te; dst = TE2; base = 0;  vv = v; }
    else if (v < 1500) { src = ce; dst = CE2; base = 32; vv = v - 1000; }
    else               { src = pe; dst = PE2; base = 64; vv = v - 1500; }
    float a = 0.f;
    #pragma unroll 8
    for (int k = 0; k < 32; ++k) a += src[vv * 32 + k] * wfw[o * 128 + base + k];
    dst[vv * 128 + (o & 63) * 2 + (o >> 6)] = a;
  } else if (blk < 1282) {
    int item = (blk - 1250) * 256 + tid;
    int j = item >> 7, o = item & 127;
    float a = 0.f;
    #pragma unroll 8
    for (int k = 0; k < 32; ++k) a += wfw[o * 128 + 96 + k] * sw2[k * 64 + j];
    WSPt[j * 128 + o] = a;
  } else if (tid < 128) {
    float a = wfb[tid];
    #pragma unroll 8
    for (int k = 0; k < 32; ++k) a += wfw[tid * 128 + 96 + k] * sb2[k];
    wfb2[(tid & 63) * 2 + (tid >> 6)] = a;
  }
}

// ---------------------------------------------------------------------------
// Encoder v5p (R13-validated, ~170us). 4 bs/block, wave <-> bs.
// ---------------------------------------------------------------------------
__global__ __launch_bounds__(256)
void encode5_kernel(
    const int* __restrict__ title_idx, const int* __restrict__ class_idx,
    const int* __restrict__ process_idx, const int* __restrict__ activity_type,
    const float* __restrict__ mouse_pos, const float* __restrict__ rect,
    const float* __restrict__ flags, const float* __restrict__ keyboard_active,
    const float* __restrict__ window_mask,
    const float* __restrict__ sw1, const float* __restrict__ sb1,
    const float* __restrict__ TE2, const float* __restrict__ CE2,
    const float* __restrict__ PE2, const float* __restrict__ WSPt,
    const float* __restrict__ wfb2,
    const float* __restrict__ mw1, const float* __restrict__ mb1,
    const float* __restrict__ mw2, const float* __restrict__ mb2,
    const float* __restrict__ act_emb, const float* __restrict__ kbw,
    const float* __restrict__ kbb,
    const float* __restrict__ afw, const float* __restrict__ afb,
    float* __restrict__ x, __hip_bfloat16* __restrict__ xb)
{
  __shared__ float h1all[4][20][64];
  __shared__ int   idxS[4][20][3];
  __shared__ float maskS[4][20];
  __shared__ float wfb2l[128];
  __shared__ float afA[4][68], afB[4][68];

  int tid = threadIdx.x;
  int w = tid >> 6, ln = tid & 63;
  int bs0 = blockIdx.x * 4;
  int bs = bs0 + w;

  if (tid < 128) wfb2l[tid] = wfb2[tid];
  for (int e = tid; e < 240; e += 256) {
    int g2 = e / 60, rem = e % 60, which = rem / 20, w_ = rem % 20;
    int rg = (bs0 + g2) * W_ + w_;
    const int* src = (which == 0) ? title_idx : (which == 1) ? class_idx : process_idx;
    idxS[g2][w_][which] = src[rg];
  }
  if (tid < 80) {
    int g2 = tid / 20, w_ = tid % 20;
    maskS[g2][w_] = window_mask[(bs0 + g2) * W_ + w_];
  }
  for (int e = tid; e < 5120; e += 256) {
    int g2 = e / 1280, rem = e - g2 * 1280;
    int w_ = rem >> 6, j = rem & 63;
    int rg = (bs0 + g2) * W_ + w_;
    float4 rc = *(const float4*)(rect + (size_t)rg * 4);
    float f0 = flags[rg * 2], f1 = flags[rg * 2 + 1];
    const float* w1 = sw1 + j * 6;
    float a = sb1[j] + w1[0]*rc.x + w1[1]*rc.y + w1[2]*rc.z + w1[3]*rc.w
                     + w1[4]*f0 + w1[5]*f1;
    h1all[g2][w_][j] = fmaxf(a, 0.f);
  }
  __syncthreads();

  float wsp0[64], wsp1[64];
  #pragma unroll
  for (int j = 0; j < 64; ++j) {
    wsp0[j] = WSPt[j * 128 + ln];
    wsp1[j] = WSPt[j * 128 + 64 + ln];
  }

  float wb0 = wfb2l[ln * 2], wb1 = wfb2l[ln * 2 + 1];
  float acc0 = 0.f, acc1 = 0.f;
  for (int w_ = 0; w_ < W_; ++w_) {
    int t  = idxS[w][w_][0];
    int ci = idxS[w][w_][1];
    int p  = idxS[w][w_][2];
    float2 gt = *(const float2*)&TE2[(size_t)t * 128 + ln * 2];
    float2 gc = *(const float2*)&CE2[(size_t)ci * 128 + ln * 2];
    float2 gp = *(const float2*)&PE2[(size_t)p * 128 + ln * 2];
    float v0 = gt.x + gc.x + gp.x + wb0;
    float v1 = gt.y + gc.y + gp.y + wb1;
    const float4* hp = (const float4*)&h1all[w][w_][0];
    #pragma unroll
    for (int j4 = 0; j4 < 16; ++j4) {
      float4 h = hp[j4];
      v0 += h.x*wsp0[4*j4] + h.y*wsp0[4*j4+1] + h.z*wsp0[4*j4+2] + h.w*wsp0[4*j4+3];
      v1 += h.x*wsp1[4*j4] + h.y*wsp1[4*j4+1] + h.z*wsp1[4*j4+2] + h.w*wsp1[4*j4+3];
    }
    float mk = maskS[w][w_];
    acc0 += fmaxf(v0, 0.f) * mk;
    acc1 += fmaxf(v1, 0.f) * mk;
  }
  {
    float v = acc0 * (1.f / (float)W_) + posenc(bs % S_, ln);
    x[(size_t)bs * D_ + ln] = v;
    xb[(size_t)bs * D_ + ln] = __float2bfloat16(v);
    v = acc1 * (1.f / (float)W_) + posenc(bs % S_, 64 + ln);
    x[(size_t)bs * D_ + 64 + ln] = v;
    xb[(size_t)bs * D_ + 64 + ln] = __float2bfloat16(v);
  }

  int bl = tid >> 6, ln63 = tid & 63;
  int bsg = bs0 + bl;
  __syncthreads();
  if (ln63 < 32) {
    float mx = mouse_pos[bsg * 2 + 0] * (1.f / 1920.f);
    float my = mouse_pos[bsg * 2 + 1] * (1.f / 1080.f);
    afA[bl][ln63] = fmaxf(mw1[ln63 * 2] * mx + mw1[ln63 * 2 + 1] * my + mb1[ln63], 0.f);
  }
  __syncthreads();
  float cv;
  if (ln63 < 32) {
    float a = mb2[ln63];
    #pragma unroll 8
    for (int k = 0; k < 32; ++k) a += mw2[ln63 * 32 + k] * afA[bl][k];
    cv = a;
  } else if (ln63 < 48) {
    cv = act_emb[activity_type[bsg] * 16 + (ln63 - 32)];
  } else {
    cv = kbw[ln63 - 48] * keyboard_active[bsg] + kbb[ln63 - 48];
  }
  __syncthreads();
  afB[bl][ln63] = cv;
  __syncthreads();
  {
    float a = afb[ln63];
    const float4* w4 = (const float4*)(afw + ln63 * 64);
    const float4* cp = (const float4*)&afB[bl][0];
    #pragma unroll
    for (int k4 = 0; k4 < 16; ++k4) {
      float4 ww = w4[k4], c2 = cp[k4];
      a += ww.x*c2.x + ww.y*c2.y + ww.z*c2.z + ww.w*c2.w;
    }
    float v = fmaxf(a, 0.f);
    int cg = 128 + ln63;
    float ovv = v + posenc(bsg % S_, cg);
    x[(size_t)bsg * D_ + cg] = ovv;
    xb[(size_t)bsg * D_ + cg] = __float2bfloat16(ovv);
  }
}

// ---------------------------------------------------------------------------
// Fused qkv + attention (R7-validated math). One block per (b,h), 256 thr.
// R14/R15: arena 40960 B => 4 blocks/CU, 1024 blocks in one scheduling wave.
//   K-loop:  Asl[0,10240) Bsl[10240,17920)
//   post-K:  Qs[0,10240) Ks[10240,20480) (alias dead Asl/Bsl)
//   Vt[33792,40960) pitch 112
//   Ps[0,33792) pitch 132 (alias Qs/Ks after post-QK^T barrier)
// FIX R15: Vt store guarded with row < S_ — R14 wrote padded rows 112..127
// past the 112-key pitch, corrupting the next d-row's keys 0..15.
// ---------------------------------------------------------------------------
__global__ __launch_bounds__(256)
void qkvattn_kernel(const __hip_bfloat16* __restrict__ xb,
                    const __hip_bfloat16* __restrict__ Wq,
                    const float* __restrict__ qb,
                    __hip_bfloat16* __restrict__ o)
{
  __shared__ __align__(16) char smem[40960];
  __hip_bfloat16* Asl = (__hip_bfloat16*)smem;             // 128*40
  __hip_bfloat16* Bsl = (__hip_bfloat16*)(smem + 10240);   // 96*40
  __hip_bfloat16* Qs  = (__hip_bfloat16*)smem;             // 128*40 (post-K)
  __hip_bfloat16* Ks  = (__hip_bfloat16*)(smem + 10240);   // 128*40 (post-K)
  __hip_bfloat16* Ps  = (__hip_bfloat16*)smem;             // 128*132 (post-QK^T)
  __hip_bfloat16* Vt  = (__hip_bfloat16*)(smem + 33792);   // 32*112

  int bh = blockIdx.x;
  int hh = bh & 7, b = bh >> 3;
  int tid = threadIdx.x, lane = tid & 63, w = tid >> 6;
  int m32 = lane & 31, half = lane >> 5;

  for (int e = tid; e < (32 * 112) / 8; e += 256)
    ((float4*)Vt)[e] = make_float4(0.f, 0.f, 0.f, 0.f);

  floatx16 acc[3];
  #pragma unroll
  for (int t = 0; t < 3; ++t)
    #pragma unroll
    for (int r = 0; r < 16; ++r) acc[t][r] = 0.f;

  for (int k0 = 0; k0 < D_; k0 += 32) {
    {
      int r = tid >> 1, h2 = tid & 1;
      int rr = r < S_ ? r : S_ - 1;
      const float4* s = (const float4*)&xb[(size_t)(b * S_ + rr) * D_ + k0 + h2 * 16];
      float4* d = (float4*)&Asl[r * 40 + h2 * 16];
      d[0] = s[0]; d[1] = s[1];
    }
    if (tid < 192) {
      int r = tid >> 1, h2 = tid & 1;
      int t = r >> 5, j = r & 31;
      float4 v0 = make_float4(0.f, 0.f, 0.f, 0.f), v1 = v0;
      if (j < DH_) {
        const float4* s =
            (const float4*)&Wq[(size_t)(t * D_ + hh * DH_ + j) * D_ + k0 + h2 * 16];
        v0 = s[0]; v1 = s[1];
      }
      float4* d = (float4*)&Bsl[r * 40 + h2 * 16];
      d[0] = v0; d[1] = v1;
    }
    __syncthreads();
    #pragma unroll
    for (int kc = 0; kc < 2; ++kc) {
      int ko = kc * 16 + half * 8;
      short8 a = *(const short8*)&Asl[(w * 32 + m32) * 40 + ko];
      #pragma unroll
      for (int t = 0; t < 3; ++t) {
        short8 bf = *(const short8*)&Bsl[(t * 32 + m32) * 40 + ko];
        acc[t] = __builtin_amdgcn_mfma_f32_32x32x16_bf16(a, bf, acc[t], 0, 0, 0);
      }
    }
    __syncthreads();   // final iter: also orders Qs/Ks writes over dead Asl/Bsl
  }
  {
    bool dv = (m32 < DH_);
    float bq = dv ? qb[0 * D_ + hh * DH_ + m32] : 0.f;
    float bk = dv ? qb[1 * D_ + hh * DH_ + m32] : 0.f;
    float bv = dv ? qb[2 * D_ + hh * DH_ + m32] : 0.f;
    #pragma unroll
    for (int r = 0; r < 16; ++r) {
      int row = w * 32 + (r & 3) + 8 * (r >> 2) + 4 * half;
      Qs[row * 40 + m32] = __float2bfloat16(dv ? acc[0][r] + bq : 0.f);
      Ks[row * 40 + m32] = __float2bfloat16(dv ? acc[1][r] + bk : 0.f);
      if (dv && row < S_) Vt[m32 * 112 + row] = __float2bfloat16(acc[2][r] + bv);
    }
  }
  __syncthreads();

  floatx16 sc[4];
  #pragma unroll
  for (int nt = 0; nt < 4; ++nt)
    #pragma unroll
    for (int r = 0; r < 16; ++r) sc[nt][r] = 0.f;
  #pragma unroll
  for (int kc = 0; kc < 2; ++kc) {
    int ko = kc * 16 + half * 8;
    short8 a = *(const short8*)&Qs[(w * 32 + m32) * 40 + ko];
    #pragma unroll
    for (int nt = 0; nt < 4; ++nt) {
      short8 bf = *(const short8*)&Ks[(nt * 32 + m32) * 40 + ko];
      sc[nt] = __builtin_amdgcn_mfma_f32_32x32x16_bf16(a, bf, sc[nt], 0, 0, 0);
    }
  }
  __syncthreads();   // all waves done reading Qs/Ks before Ps overwrites them

  const float scale = 0.20412414523193154f;  // 1/sqrt(24)
  float rinv[16];
  #pragma unroll
  for (int r = 0; r < 16; ++r) {
    float mx = -1e30f;
    #pragma unroll
    for (int nt = 0; nt < 4; ++nt) {
      float s = sc[nt][r] * scale;
      if (nt == 3 && m32 >= 4) s = -1e30f;   // keys >= 100
      sc[nt][r] = s;
      mx = fmaxf(mx, s);
    }
    #pragma unroll
    for (int off = 1; off < 32; off <<= 1) mx = fmaxf(mx, __shfl_xor(mx, off));
    float sum = 0.f;
    #pragma unroll
    for (int nt = 0; nt < 4; ++nt) {
      float e = expf(sc[nt][r] - mx);
      sc[nt][r] = e;
      sum += e;
    }
    #pragma unroll
    for (int off = 1; off < 32; off <<= 1) sum += __shfl_xor(sum, off);
    rinv[r] = 1.f / sum;
  }
  #pragma unroll
  for (int r = 0; r < 16; ++r) {
    int rowl = (r & 3) + 8 * (r >> 2) + 4 * half;
    #pragma unroll
    for (int nt = 0; nt < 4; ++nt)
      Ps[(w * 32 + rowl) * 132 + nt * 32 + m32] = __float2bfloat16(sc[nt][r]);
  }
  // Ps is wave-private — no barrier.

  floatx16 ov;
  #pragma unroll
  for (int r = 0; r < 16; ++r) ov[r] = 0.f;
  #pragma unroll
  for (int kt = 0; kt < 7; ++kt) {       // 112 keys (100..111: P=0, Vt=0)
    int ko = kt * 16 + half * 8;
    short8 a = ld_frag8(&Ps[(w * 32 + m32) * 132 + ko]);
    short8 bf = *(const short8*)&Vt[m32 * 112 + ko];
    ov = __builtin_amdgcn_mfma_f32_32x32x16_bf16(a, bf, ov, 0, 0, 0);
  }
  #pragma unroll
  for (int r = 0; r < 16; ++r) {
    int rowl = (r & 3) + 8 * (r >> 2) + 4 * half;
    int q = w * 32 + rowl;
    if (m32 < DH_ && q < S_)
      o[((size_t)(b * S_ + q)) * D_ + hh * DH_ + m32] =
          __float2bfloat16(ov[r] * rinv[r]);
  }
}

// ---------------------------------------------------------------------------
// Fused out-proj+LN1 + ff1+ff2+LN2 (validated R10-R13). 200 blocks, 256 thr.
// ---------------------------------------------------------------------------
__global__ __launch_bounds__(256)
void outffln_kernel(const __hip_bfloat16* __restrict__ attb,
                    const __hip_bfloat16* __restrict__ Wo, const float* __restrict__ bo,
                    const float* __restrict__ g1, const float* __restrict__ b1v,
                    const __hip_bfloat16* __restrict__ W1, const float* __restrict__ b1,
                    const __hip_bfloat16* __restrict__ W2, const float* __restrict__ b2,
                    const float* __restrict__ g2, const float* __restrict__ b2v,
                    float* __restrict__ x, __hip_bfloat16* __restrict__ xb)
{
  __shared__ __align__(16) char arena[59904];
  __hip_bfloat16* AslA = (__hip_bfloat16*)arena;             // 64*40
  __hip_bfloat16* BslA = (__hip_bfloat16*)(arena + 5120);    // 192*40
  __hip_bfloat16* C1   = (__hip_bfloat16*)arena;             // 64*260
  __hip_bfloat16* AslB = (__hip_bfloat16*)(arena + 33280);   // 64*40
  __hip_bfloat16* BslB = (__hip_bfloat16*)(arena + 38400);   // 256*40
  float (*psum)[2] = (float(*)[2])(arena + 58880);
  float (*psq)[2]  = (float(*)[2])(arena + 59392);

  int tid = threadIdx.x, lane = tid & 63, w = tid >> 6;
  int m32 = lane & 31, half = lane >> 5;
  int mt = w & 1, ng = w >> 1;
  int bm = blockIdx.x * 64;

  // ========= phase A: out-proj + residual + LN1 =========
  floatx16 accA[3];
  #pragma unroll
  for (int j = 0; j < 3; ++j)
    #pragma unroll
    for (int r = 0; r < 16; ++r) accA[j][r] = 0.f;

  for (int k0 = 0; k0 < D_; k0 += 32) {
    if (tid < 128) {
      int r = tid >> 1, h = tid & 1;
      const float4* s = (const float4*)(attb + (size_t)(bm + r) * D_ + k0 + h * 16);
      float4* d = (float4*)&AslA[r * 40 + h * 16];
      d[0] = s[0]; d[1] = s[1];
    }
    for (int e = tid; e < 384; e += 256) {
      int r = e >> 1, h = e & 1;
      const float4* s = (const float4*)(Wo + (size_t)r * D_ + k0 + h * 16);
      float4* d = (float4*)&BslA[r * 40 + h * 16];
      d[0] = s[0]; d[1] = s[1];
    }
    __syncthreads();
    #pragma unroll
    for (int kc = 0; kc < 2; ++kc) {
      int ko = kc * 16 + half * 8;
      short8 a = *(const short8*)&AslA[(mt * 32 + m32) * 40 + ko];
      #pragma unroll
      for (int j = 0; j < 3; ++j) {
        short8 bf = *(const short8*)&BslA[((ng * 3 + j) * 32 + m32) * 40 + ko];
        accA[j] = __builtin_amdgcn_mfma_f32_32x32x16_bf16(a, bf, accA[j], 0, 0, 0);
      }
    }
    __syncthreads();
  }
  {
    int rowb = mt * 32 + 4 * half;
    #pragma unroll
    for (int r = 0; r < 16; ++r) {
      int rl = rowb + (r & 3) + 8 * (r >> 2);
      int row = bm + rl;
      float p = 0.f;
      #pragma unroll
      for (int j = 0; j < 3; ++j) {
        int col = (ng * 3 + j) * 32 + m32;
        float t = accA[j][r] + bo[col] + x[(size_t)row * D_ + col];
        accA[j][r] = t;
        p += t;
      }
      #pragma unroll
      for (int off = 1; off < 32; off <<= 1) p += __shfl_xor(p, off);
      if (m32 == 0) psum[rl][ng] = p;
    }
    __syncthreads();
    float mean[16];
    #pragma unroll
    for (int r = 0; r < 16; ++r) {
      int rl = rowb + (r & 3) + 8 * (r >> 2);
      mean[r] = (psum[rl][0] + psum[rl][1]) * (1.f / (float)D_);
    }
    #pragma unroll
    for (int r = 0; r < 16; ++r) {
      int rl = rowb + (r & 3) + 8 * (r >> 2);
      float s = 0.f;
      #pragma unroll
      for (int j = 0; j < 3; ++j) { float dd = accA[j][r] - mean[r]; s += dd * dd; }
      #pragma unroll
      for (int off = 1; off < 32; off <<= 1) s += __shfl_xor(s, off);
      if (m32 == 0) psq[rl][ng] = s;
    }
    __syncthreads();
    #pragma unroll
    for (int r = 0; r < 16; ++r) {
      int rl = rowb + (r & 3) + 8 * (r >> 2);
      int row = bm + rl;
      float inv = rsqrtf((psq[rl][0] + psq[rl][1]) * (1.f / (float)D_) + 1e-5f);
      #pragma unroll
      for (int j = 0; j < 3; ++j) {
        int col = (ng * 3 + j) * 32 + m32;
        float ovv = (accA[j][r] - mean[r]) * inv * g1[col] + b1v[col];
        x[(size_t)row * D_ + col] = ovv;
        xb[(size_t)row * D_ + col] = __float2bfloat16(ovv);
      }
    }
  }
  __syncthreads();

  // ========= phase B: ff1 + ff2 + residual + LN2 =========
  floatx16 acc1[4];
  #pragma unroll
  for (int j = 0; j < 4; ++j)
    #pragma unroll
    for (int r = 0; r < 16; ++r) acc1[j][r] = 0.f;

  for (int k0 = 0; k0 < D_; k0 += 32) {
    if (tid < 128) {
      int r = tid >> 1, h = tid & 1;
      const float4* s = (const float4*)(xb + (size_t)(bm + r) * D_ + k0 + h * 16);
      float4* d = (float4*)&AslB[r * 40 + h * 16];
      d[0] = s[0]; d[1] = s[1];
    }
    for (int e = tid; e < 512; e += 256) {
      int r = e >> 1, h = e & 1;
      const float4* s = (const float4*)(W1 + (size_t)r * D_ + k0 + h * 16);
      float4* d = (float4*)&BslB[r * 40 + h * 16];
      d[0] = s[0]; d[1] = s[1];
    }
    __syncthreads();
    #pragma unroll
    for (int kc = 0; kc < 2; ++kc) {
      int ko = kc * 16 + half * 8;
      short8 a = *(const short8*)&AslB[(mt * 32 + m32) * 40 + ko];
      #pragma unroll
      for (int j = 0; j < 4; ++j) {
        short8 bf = *(const short8*)&BslB[((ng * 4 + j) * 32 + m32) * 40 + ko];
        acc1[j] = __builtin_amdgcn_mfma_f32_32x32x16_bf16(a, bf, acc1[j], 0, 0, 0);
      }
    }
    __syncthreads();
  }
  {
    int rowb = mt * 32 + 4 * half;
    #pragma unroll
    for (int j = 0; j < 4; ++j) {
      int col = (ng * 4 + j) * 32 + m32;
      float cb = b1[col];
      #pragma unroll
      for (int r = 0; r < 16; ++r) {
        int row = rowb + (r & 3) + 8 * (r >> 2);
        C1[row * 260 + col] = __float2bfloat16(fmaxf(acc1[j][r] + cb, 0.f));
      }
    }
  }
  __syncthreads();

  floatx16 acc2[3];
  #pragma unroll
  for (int j = 0; j < 3; ++j)
    #pragma unroll
    for (int r = 0; r < 16; ++r) acc2[j][r] = 0.f;

  for (int k0 = 0; k0 < DFF_; k0 += 32) {
    for (int e = tid; e < 384; e += 256) {
      int r = e >> 1, h = e & 1;
      const float4* s = (const float4*)(W2 + (size_t)r * DFF_ + k0 + h * 16);
      float4* d = (float4*)&BslB[r * 40 + h * 16];
      d[0] = s[0]; d[1] = s[1];
    }
    __syncthreads();
    #pragma unroll
    for (int kc = 0; kc < 2; ++kc) {
      int ko = kc * 16 + half * 8;
      short8 a = ld_frag8(&C1[(mt * 32 + m32) * 260 + k0 + ko]);
      #pragma unroll
      for (int j = 0; j < 3; ++j) {
        short8 bf = *(const short8*)&BslB[((ng * 3 + j) * 32 + m32) * 40 + ko];
        acc2[j] = __builtin_amdgcn_mfma_f32_32x32x16_bf16(a, bf, acc2[j], 0, 0, 0);
      }
    }
    __syncthreads();
  }

  int rowb = mt * 32 + 4 * half;
  #pragma unroll
  for (int r = 0; r < 16; ++r) {
    int rl = rowb + (r & 3) + 8 * (r >> 2);
    int row = bm + rl;
    float p = 0.f;
    #pragma unroll
    for (int j = 0; j < 3; ++j) {
      int col = (ng * 3 + j) * 32 + m32;
      float t = acc2[j][r] + b2[col] + x[(size_t)row * D_ + col];
      acc2[j][r] = t;
      p += t;
    }
    #pragma unroll
    for (int off = 1; off < 32; off <<= 1) p += __shfl_xor(p, off);
    if (m32 == 0) psum[rl][ng] = p;
  }
  __syncthreads();
  float mean[16];
  #pragma unroll
  for (int r = 0; r < 16; ++r) {
    int rl = rowb + (r & 3) + 8 * (r >> 2);
    mean[r] = (psum[rl][0] + psum[rl][1]) * (1.f / (float)D_);
  }
  #pragma unroll
  for (int r = 0; r < 16; ++r) {
    int rl = rowb + (r & 3) + 8 * (r >> 2);
    float s = 0.f;
    #pragma unroll
    for (int j = 0; j < 3; ++j) { float dd = acc2[j][r] - mean[r]; s += dd * dd; }
    #pragma unroll
    for (int off = 1; off < 32; off <<= 1) s += __shfl_xor(s, off);
    if (m32 == 0) psq[rl][ng] = s;
  }
  __syncthreads();
  #pragma unroll
  for (int r = 0; r < 16; ++r) {
    int rl = rowb + (r & 3) + 8 * (r >> 2);
    int row = bm + rl;
    float inv = rsqrtf((psq[rl][0] + psq[rl][1]) * (1.f / (float)D_) + 1e-5f);
    #pragma unroll
    for (int j = 0; j < 3; ++j) {
      int col = (ng * 3 + j) * 32 + m32;
      float ovv = (acc2[j][r] - mean[r]) * inv * g2[col] + b2v[col];
      x[(size_t)row * D_ + col] = ovv;
      xb[(size_t)row * D_ + col] = __float2bfloat16(ovv);
    }
  }
}

// ---------------------------------------------------------------------------
// Head (fp32): one block per (w,b) slot.
// ---------------------------------------------------------------------------
__global__ __launch_bounds__(256)
void head_kernel(const float* __restrict__ x, const float* __restrict__ noise,
                 const float* __restrict__ pw1, const float* __restrict__ pb1,
                 const float* __restrict__ pw2, const float* __restrict__ pb2,
                 const float* __restrict__ ew1, const float* __restrict__ eb1,
                 const float* __restrict__ ew2, const float* __restrict__ eb2,
                 float* __restrict__ out)
{
  int idx = blockIdx.x;
  int b = idx & 127, w = idx >> 7;
  int tid = threadIdx.x;
  __shared__ float slot[192];
  __shared__ float ph[256];
  __shared__ float eh[128];
  if (tid < 192)
    slot[tid] = x[((size_t)b * S_ + (S_ - 1)) * D_ + tid]
              + noise[((size_t)w * B_ + b) * D_ + tid] * 0.1f;
  __syncthreads();
  {
    const float4* wr = (const float4*)(pw1 + (size_t)tid * D_);
    const float4* sp = (const float4*)slot;
    float a = pb1[tid];
    #pragma unroll 12
    for (int k = 0; k < 48; ++k) {
      float4 wv = wr[k], sv = sp[k];
      a += wv.x*sv.x + wv.y*sv.y + wv.z*sv.z + wv.w*sv.w;
    }
    ph[tid] = fmaxf(a, 0.f);
  }
  if (tid < 128) {
    const float4* wr = (const float4*)(ew1 + (size_t)tid * D_);
    const float4* sp = (const float4*)slot;
    float a = eb1[tid];
    #pragma unroll 12
    for (int k = 0; k < 48; ++k) {
      float4 wv = wr[k], sv = sp[k];
      a += wv.x*sv.x + wv.y*sv.y + wv.z*sv.z + wv.w*sv.w;
    }
    eh[tid] = fmaxf(a, 0.f);
  }
  __syncthreads();
  if (tid < 4) {
    float a = pb2[tid];
    const float4* wr = (const float4*)(pw2 + tid * 256);
    const float4* pp = (const float4*)ph;
    for (int k = 0; k < 64; ++k) {
      float4 wv = wr[k], pv = pp[k];
      a += wv.x*pv.x + wv.y*pv.y + wv.z*pv.z + wv.w*pv.w;
    }
    out[((size_t)b * W_ + w) * 4 + tid] = a;
  }
  if (tid == 4) {
    float a = eb2[0];
    const float4* wr = (const float4*)ew2;
    const float4* pp = (const float4*)eh;
    for (int k = 0; k < 32; ++k) {
      float4 wv = wr[k], pv = pp[k];
      a += wv.x*pv.x + wv.y*pv.y + wv.z*pv.z + wv.w*pv.w;
    }
    out[(size_t)B_ * W_ * 4 + (size_t)b * W_ + w] = 1.f / (1.f + expf(-a));
  }
}

// ---------------------------------------------------------------------------
extern "C" void kernel_launch(void* const* d_in, const int* in_sizes, int n_in,
                              void* d_out, int out_size, void* d_ws, size_t ws_size,
                              hipStream_t stream)
{
  const int*   title_idx       = (const int*)  d_in[0];
  const int*   class_idx       = (const int*)  d_in[1];
  const int*   process_idx     = (const int*)  d_in[2];
  const int*   activity_type   = (const int*)  d_in[3];
  const float* mouse_pos       = (const float*)d_in[4];
  const float* rect            = (const float*)d_in[5];
  const float* flags           = (const float*)d_in[6];
  const float* keyboard_active = (const float*)d_in[7];
  const float* window_mask     = (const float*)d_in[8];
  const float* noise           = (const float*)d_in[9];
  const float* title_emb       = (const float*)d_in[10];
  const float* class_emb       = (const float*)d_in[11];
  const float* process_emb     = (const float*)d_in[12];
  const float* spatial_w1      = (const float*)d_in[13];
  const float* spatial_b1      = (const float*)d_in[14];
  const float* spatial_w2      = (const float*)d_in[15];
  const float* spatial_b2      = (const float*)d_in[16];
  const float* wfuse_w         = (const float*)d_in[17];
  const float* wfuse_b         = (const float*)d_in[18];
  const float* mouse_w1        = (const float*)d_in[19];
  const float* mouse_b1        = (const float*)d_in[20];
  const float* mouse_w2        = (const float*)d_in[21];
  const float* mouse_b2        = (const float*)d_in[22];
  const float* act_emb         = (const float*)d_in[23];
  const float* kbd_w           = (const float*)d_in[24];
  const float* kbd_b           = (const float*)d_in[25];
  const float* afuse_w         = (const float*)d_in[26];
  const float* afuse_b         = (const float*)d_in[27];
  const float* qkv_w           = (const float*)d_in[28];
  const float* qkv_b           = (const float*)d_in[29];
  const float* out_w           = (const float*)d_in[30];
  const float* out_b           = (const float*)d_in[31];
  const float* ff1_w           = (const float*)d_in[32];
  const float* ff1_b           = (const float*)d_in[33];
  const float* ff2_w           = (const float*)d_in[34];
  const float* ff2_b           = (const float*)d_in[35];
  const float* ln1_g           = (const float*)d_in[36];
  const float* ln1_b           = (const float*)d_in[37];
  const float* ln2_g           = (const float*)d_in[38];
  const float* ln2_b           = (const float*)d_in[39];
  const float* proj_w1         = (const float*)d_in[40];
  const float* proj_b1         = (const float*)d_in[41];
  const float* proj_w2         = (const float*)d_in[42];
  const float* proj_b2         = (const float*)d_in[43];
  const float* ex_w1           = (const float*)d_in[44];
  const float* ex_b1           = (const float*)d_in[45];
  const float* ex_w2           = (const float*)d_in[46];
  const float* ex_b2           = (const float*)d_in[47];

  float* out = (float*)d_out;

  // workspace layout
  float* x = (float*)d_ws;                                      // BS*192 f32
  __hip_bfloat16* xb   = (__hip_bfloat16*)(x + (size_t)BS_ * D_);
  __hip_bfloat16* attb = xb   + (size_t)BS_ * D_;
  __hip_bfloat16* wqb  = attb + (size_t)BS_ * D_;
  __hip_bfloat16* wob  = wqb  + (size_t)L_ * THREED_ * D_;
  __hip_bfloat16* wf1b = wob  + (size_t)L_ * D_ * D_;
  __hip_bfloat16* wf2b = wf1b + (size_t)L_ * DFF_ * D_;
  float* TE2  = (float*)(wf2b + (size_t)L_ * D_ * DFF_);        // 1000*128
  float* CE2  = TE2  + 1000 * 128;                              // 500*128
  float* PE2  = CE2  + 500 * 128;                               // 1000*128
  float* WSPt = PE2  + 1000 * 128;                              // 64*128
  float* wfb2 = WSPt + 64 * 128;                                // 128
  (void)ws_size; (void)n_in; (void)in_sizes; (void)out_size;

  convertprep_kernel<<<2003, 256, 0, stream>>>(
      qkv_w, wqb, out_w, wob, ff1_w, wf1b, ff2_w, wf2b,
      title_emb, class_emb, process_emb, wfuse_w, wfuse_b,
      spatial_w2, spatial_b2, TE2, CE2, PE2, WSPt, wfb2);

  encode5_kernel<<<BS_ / 4, 256, 0, stream>>>(
      title_idx, class_idx, process_idx, activity_type, mouse_pos, rect, flags,
      keyboard_active, window_mask, spatial_w1, spatial_b1,
      TE2, CE2, PE2, WSPt, wfb2,
      mouse_w1, mouse_b1, mouse_w2, mouse_b2, act_emb, kbd_w, kbd_b,
      afuse_w, afuse_b, x, xb);

  for (int l = 0; l < L_; ++l) {
    qkvattn_kernel<<<B_ * H_, 256, 0, stream>>>(
        xb, wqb + (size_t)l * THREED_ * D_, qkv_b + (size_t)l * THREED_, attb);
    outffln_kernel<<<BS_ / 64, 256, 0, stream>>>(
        attb, wob + (size_t)l * D_ * D_, out_b + (size_t)l * D_,
        ln1_g + (size_t)l * D_, ln1_b + (size_t)l * D_,
        wf1b + (size_t)l * DFF_ * D_, ff1_b + (size_t)l * DFF_,
        wf2b + (size_t)l * D_ * DFF_, ff2_b + (size_t)l * D_,
        ln2_g + (size_t)l * D_, ln2_b + (size_t)l * D_, x, xb);
  }

  head_kernel<<<W_ * B_, 256, 0, stream>>>(
      x, noise, proj_w1, proj_b1, proj_w2, proj_b2,
      ex_w1, ex_b1, ex_w2, ex_b2, out);
}